// Round 1
// baseline (3181.093 us; speedup 1.0000x reference)
//
#include <hip/hip_runtime.h>
#include <hip/hip_bf16.h>

// Problem: B=4, N0=2048 (split into N=1024 diff + 1024 cond), C=768, H=12, hd=64
// All fp32. Pipeline:
//   1. qkv_d = x[:, :N] @ w_qkv_diff ; qkv_c = x[:, N:] @ w_qkv_cond  -> (B,H,N,64) x6
//   2. o_attn_d = softmax(q_d k_d^T / 8) v_d           -> (B,N,C)
//   3. o_proj_d = o_attn_d @ w_proj_diff + b_proj_diff -> (B,N,C)
//   4. out[:, :N] = softmax(q_c k_c^T / 8) o_proj_d    (attn_cond applied to projected diff)
//   5. o_attn_c = softmax(q_c k_c^T / 8) v_c           -> (B,N,C)
//   6. out[:, N:] = o_attn_c @ w_proj_cond + b_proj_cond

#define C_DIM 768
#define HEADS 12
#define HD 64
#define NSEQ 1024
#define BATCH 4

// ---------------------------------------------------------------------------
// QKV GEMM: per half (diff/cond), M=4096 (b,n), K=768, Ncols=2304.
// Each 64-wide column tile is exactly one (t in {q,k,v}, h) pair; output is
// scattered directly into (B,H,N,64)-layout q/k/v slots in workspace.
// 64x64 tile, BK=16, 256 threads, 4x4 micro-tile per thread.
// ---------------------------------------------------------------------------
__global__ __launch_bounds__(256) void qkv_gemm_k(
    const float* __restrict__ x,
    const float* __restrict__ w_d,
    const float* __restrict__ w_c,
    float* __restrict__ ws)
{
  __shared__ float As[16][68];  // k-major, +4 pad keeps float4 reads 16B-aligned
  __shared__ float Bs[16][64];
  const int tid  = threadIdx.x;
  const int half = blockIdx.z;
  const float* __restrict__ w = half ? w_c : w_d;
  const int m0 = blockIdx.y * 64;      // 0..4095
  const int b  = m0 >> 10;
  const int n0 = m0 & 1023;
  const int ctile = blockIdx.x;        // 0..35
  const int t = ctile / 12;            // q/k/v
  const int h = ctile % 12;
  const size_t SZ = (size_t)BATCH * HEADS * NSEQ * HD;  // 3145728
  const size_t a_base = (size_t)b * (2048 * 768) + (size_t)(n0 + half * 1024) * 768;
  float* __restrict__ out = ws + (size_t)half * 3 * SZ + (size_t)t * SZ
                          + ((size_t)(b * HEADS + h) * NSEQ + n0) * HD;

  const int a_r = tid >> 2;            // A tile: row 0..63
  const int a_k = (tid & 3) * 4;       //          k 0..15 (float4)
  const int b_k = tid >> 4;            // B tile: k 0..15
  const int b_c = (tid & 15) * 4;      //          col 0..63 (float4)
  const int col0 = ctile * 64;
  const int tx = tid & 15;
  const int ty = tid >> 4;

  float acc[4][4] = {};
  for (int k0 = 0; k0 < 768; k0 += 16) {
    float4 av = *(const float4*)(x + a_base + (size_t)a_r * 768 + (k0 + a_k));
    float4 bv = *(const float4*)(w + (size_t)(k0 + b_k) * 2304 + (col0 + b_c));
    As[a_k + 0][a_r] = av.x;
    As[a_k + 1][a_r] = av.y;
    As[a_k + 2][a_r] = av.z;
    As[a_k + 3][a_r] = av.w;
    *(float4*)&Bs[b_k][b_c] = bv;
    __syncthreads();
#pragma unroll
    for (int kk = 0; kk < 16; ++kk) {
      float ar[4], br[4];
      *(float4*)ar = *(const float4*)&As[kk][ty * 4];
      *(float4*)br = *(const float4*)&Bs[kk][tx * 4];
#pragma unroll
      for (int i = 0; i < 4; ++i)
#pragma unroll
        for (int j = 0; j < 4; ++j)
          acc[i][j] += ar[i] * br[j];
    }
    __syncthreads();
  }
#pragma unroll
  for (int i = 0; i < 4; ++i) {
    float4 o = make_float4(acc[i][0], acc[i][1], acc[i][2], acc[i][3]);
    *(float4*)(out + (size_t)(ty * 4 + i) * HD + tx * 4) = o;
  }
}

// ---------------------------------------------------------------------------
// Projection GEMM: A (4096x768, (B,N,C) contiguous) @ W (768x768) + bias.
// Flexible output mapping: out[b*out_bstride + (n_off + n)*768 + col].
// ---------------------------------------------------------------------------
__global__ __launch_bounds__(256) void proj_gemm_k(
    const float* __restrict__ A,
    const float* __restrict__ W,
    const float* __restrict__ bias,
    float* __restrict__ out,
    long out_bstride, int n_off)
{
  __shared__ float As[16][68];
  __shared__ float Bs[16][64];
  const int tid = threadIdx.x;
  const int m0 = blockIdx.y * 64;
  const int b  = m0 >> 10;
  const int n0 = m0 & 1023;
  const int col0 = blockIdx.x * 64;

  const int a_r = tid >> 2;
  const int a_k = (tid & 3) * 4;
  const int b_k = tid >> 4;
  const int b_c = (tid & 15) * 4;
  const int tx = tid & 15;
  const int ty = tid >> 4;

  float acc[4][4] = {};
  for (int k0 = 0; k0 < 768; k0 += 16) {
    float4 av = *(const float4*)(A + (size_t)(m0 + a_r) * 768 + (k0 + a_k));
    float4 bv = *(const float4*)(W + (size_t)(k0 + b_k) * 768 + (col0 + b_c));
    As[a_k + 0][a_r] = av.x;
    As[a_k + 1][a_r] = av.y;
    As[a_k + 2][a_r] = av.z;
    As[a_k + 3][a_r] = av.w;
    *(float4*)&Bs[b_k][b_c] = bv;
    __syncthreads();
#pragma unroll
    for (int kk = 0; kk < 16; ++kk) {
      float ar[4], br[4];
      *(float4*)ar = *(const float4*)&As[kk][ty * 4];
      *(float4*)br = *(const float4*)&Bs[kk][tx * 4];
#pragma unroll
      for (int i = 0; i < 4; ++i)
#pragma unroll
        for (int j = 0; j < 4; ++j)
          acc[i][j] += ar[i] * br[j];
    }
    __syncthreads();
  }
  float* op = out + (size_t)b * out_bstride + (size_t)(n_off + n0) * 768 + col0;
#pragma unroll
  for (int i = 0; i < 4; ++i) {
    float4 o = make_float4(acc[i][0] + bias[col0 + tx * 4 + 0],
                           acc[i][1] + bias[col0 + tx * 4 + 1],
                           acc[i][2] + bias[col0 + tx * 4 + 2],
                           acc[i][3] + bias[col0 + tx * 4 + 3]);
    *(float4*)(op + (size_t)(ty * 4 + i) * 768 + tx * 4) = o;
  }
}

// ---------------------------------------------------------------------------
// Flash-style attention, fp32. One thread per q-row (q row + 64-wide acc in
// registers), K/V tiles (32x64) staged in LDS, online softmax with
// branch-skipped rescale. V and output are stride-parameterized so the same
// kernel consumes (B,H,N,64) tensors or (B,N,C) tensors, and writes (B,N,C).
// grid (N/128, H, B), block 128 (2 waves).
// ---------------------------------------------------------------------------
__global__ __launch_bounds__(128) void attn_k(
    const float* __restrict__ q,    // (B,H,N,64)
    const float* __restrict__ k,    // (B,H,N,64)
    const float* __restrict__ v,    // strided
    long v_bstride, long v_hstride, long v_rstride,
    float* __restrict__ out,        // (B, n, 768) layout
    long o_bstride)
{
  __shared__ float Ks[32][64];
  __shared__ float Vs[32][64];
  const int b = blockIdx.z, h = blockIdx.y;
  const int row = blockIdx.x * 128 + threadIdx.x;
  const size_t qk_base = (size_t)(b * HEADS + h) * NSEQ * HD;

  float qr[64];
  const float* qp = q + qk_base + (size_t)row * HD;
#pragma unroll
  for (int i = 0; i < 16; ++i) {
    float4 tq = *(const float4*)(qp + i * 4);
    qr[i * 4 + 0] = tq.x; qr[i * 4 + 1] = tq.y;
    qr[i * 4 + 2] = tq.z; qr[i * 4 + 3] = tq.w;
  }
  float acc[64];
#pragma unroll
  for (int d = 0; d < 64; ++d) acc[d] = 0.f;
  float m_run = -3.0e38f, l_run = 0.f;

  const float* kp = k + qk_base;
  const float* vp = v + (size_t)b * v_bstride + (size_t)h * v_hstride;

  for (int j0 = 0; j0 < NSEQ; j0 += 32) {
    __syncthreads();
#pragma unroll
    for (int l = 0; l < 4; ++l) {
      int idx = l * 128 + threadIdx.x;  // 0..511
      int r   = idx >> 4;               // 0..31
      int c4  = (idx & 15) * 4;
      *(float4*)&Ks[r][c4] = *(const float4*)(kp + (size_t)(j0 + r) * HD + c4);
      *(float4*)&Vs[r][c4] = *(const float4*)(vp + (size_t)(j0 + r) * v_rstride + c4);
    }
    __syncthreads();
    for (int j = 0; j < 32; ++j) {
      float s = 0.f;
#pragma unroll
      for (int d = 0; d < 64; ++d) s += qr[d] * Ks[j][d];
      s *= 0.125f;  // hd^-0.5
      if (s > m_run) {
        float corr = __expf(m_run - s);
        l_run *= corr;
#pragma unroll
        for (int d = 0; d < 64; ++d) acc[d] *= corr;
        m_run = s;
      }
      float p = __expf(s - m_run);
      l_run += p;
#pragma unroll
      for (int d = 0; d < 64; ++d) acc[d] += p * Vs[j][d];
    }
  }
  float inv = 1.f / l_run;
  float* op = out + (size_t)b * o_bstride + (size_t)row * 768 + h * 64;
#pragma unroll
  for (int i = 0; i < 16; ++i) {
    float4 o = make_float4(acc[i * 4 + 0] * inv, acc[i * 4 + 1] * inv,
                           acc[i * 4 + 2] * inv, acc[i * 4 + 3] * inv);
    *(float4*)(op + i * 4) = o;
  }
}

// ---------------------------------------------------------------------------
extern "C" void kernel_launch(void* const* d_in, const int* in_sizes, int n_in,
                              void* d_out, int out_size, void* d_ws, size_t ws_size,
                              hipStream_t stream)
{
  const float* x           = (const float*)d_in[0];
  const float* w_qkv_diff  = (const float*)d_in[1];
  const float* w_qkv_cond  = (const float*)d_in[2];
  const float* w_proj_diff = (const float*)d_in[3];
  const float* b_proj_diff = (const float*)d_in[4];
  const float* w_proj_cond = (const float*)d_in[5];
  const float* b_proj_cond = (const float*)d_in[6];
  float* out = (float*)d_out;
  float* ws  = (float*)d_ws;

  const size_t SZ = (size_t)BATCH * HEADS * NSEQ * HD;  // 3145728 floats
  float* q_d      = ws + 0 * SZ;
  float* v_d      = ws + 2 * SZ;   // k_d = ws + 1*SZ (addressed via q_d base)
  float* q_c      = ws + 3 * SZ;
  float* k_d      = ws + 1 * SZ;
  float* k_c      = ws + 4 * SZ;
  float* v_c      = ws + 5 * SZ;
  float* o_attn_d = ws + 6 * SZ;   // (B,N,C)
  float* o_proj_d = ws + 7 * SZ;   // (B,N,C)
  float* o_attn_c = ws + 0 * SZ;   // reuse q_d slot (dead after step 2)
  // total ws use: 8*SZ*4B = 96 MB

  // 1. QKV projections, both halves (z = half)
  qkv_gemm_k<<<dim3(36, 64, 2), 256, 0, stream>>>(x, w_qkv_diff, w_qkv_cond, ws);

  // 2. attn_diff @ v_d -> o_attn_d (B,N,C)
  attn_k<<<dim3(8, 12, 4), 128, 0, stream>>>(
      q_d, k_d, v_d,
      (long)HEADS * NSEQ * HD, (long)NSEQ * HD, (long)HD,
      o_attn_d, (long)NSEQ * C_DIM);

  // 3. o_proj_d = o_attn_d @ w_proj_diff + b
  proj_gemm_k<<<dim3(12, 64), 256, 0, stream>>>(
      o_attn_d, w_proj_diff, b_proj_diff, o_proj_d, (long)NSEQ * C_DIM, 0);

  // 4. attn_cond @ o_proj_d -> out[:, :N, :]
  attn_k<<<dim3(8, 12, 4), 128, 0, stream>>>(
      q_c, k_c, o_proj_d,
      (long)NSEQ * C_DIM, (long)HD, (long)C_DIM,
      out, (long)2048 * C_DIM);

  // 5. attn_cond @ v_c -> o_attn_c (B,N,C)
  attn_k<<<dim3(8, 12, 4), 128, 0, stream>>>(
      q_c, k_c, v_c,
      (long)HEADS * NSEQ * HD, (long)NSEQ * HD, (long)HD,
      o_attn_c, (long)NSEQ * C_DIM);

  // 6. out[:, N:, :] = o_attn_c @ w_proj_cond + b
  proj_gemm_k<<<dim3(12, 64), 256, 0, stream>>>(
      o_attn_c, w_proj_cond, b_proj_cond, out, (long)2048 * C_DIM, 1024);
}

// Round 2
// 877.884 us; speedup vs baseline: 3.6236x; 3.6236x over previous
//
#include <hip/hip_runtime.h>
#include <hip/hip_bf16.h>

// B=4, N0=2048 (N=1024 diff + 1024 cond), C=768, H=12, hd=64. All fp32 I/O.
//   1. qkv both streams (fp32 GEMM, epilogue -> split bf16 hi/lo; V transposed)
//   2. o_attn_d = attn(q_d,k_d,v_d)          [MFMA split-bf16]  -> fp32 (B,N,C)
//   3. vt2      = (o_attn_d @ w_proj_diff + b) transposed split -> (B,H,64,N) hi/lo
//   4. out[:, :N] = attn(q_c,k_c, vt2)       [MFMA]
//   5. o_attn_c = attn(q_c,k_c,v_c)          [MFMA]             -> fp32 (B,N,C)
//   6. out[:, N:] = o_attn_c @ w_proj_cond + b                  [fp32 GEMM]

#define C_DIM 768
#define HEADS 12
#define HD 64
#define NSEQ 1024
#define BATCH 4

typedef short bf16x8 __attribute__((ext_vector_type(8)));
typedef float f32x4 __attribute__((ext_vector_type(4)));
typedef unsigned int u32x4v __attribute__((ext_vector_type(4)));

__device__ __forceinline__ unsigned short f2bf(float x) {
  __hip_bfloat16 h = __float2bfloat16(x);
  return *reinterpret_cast<unsigned short*>(&h);
}
__device__ __forceinline__ float bf2f(unsigned short u) {
  __hip_bfloat16 h = *reinterpret_cast<__hip_bfloat16*>(&u);
  return __bfloat162float(h);
}
__device__ __forceinline__ void split2(float x, unsigned short& hi, unsigned short& lo) {
  unsigned short h = f2bf(x);
  lo = f2bf(x - bf2f(h));
  hi = h;
}

// ---------------------------------------------------------------------------
// QKV GEMM (fp32 compute): 64x64 tile, BK=16, 256 thr, 4x4 micro-tile.
// Epilogue: split bf16. q,k row-major (B,H,N,64); v transposed (B,H,64,N).
// ws array order per stream: q_hi,q_lo,k_hi,k_lo,vt_hi,vt_lo (each SZ elems).
// ---------------------------------------------------------------------------
__global__ __launch_bounds__(256) void qkv_gemm_split_k(
    const float* __restrict__ x,
    const float* __restrict__ w_d,
    const float* __restrict__ w_c,
    unsigned short* __restrict__ ws)
{
  __shared__ float As[16][68];
  __shared__ float Bs[16][64];
  const int tid  = threadIdx.x;
  const int half = blockIdx.z;
  const float* __restrict__ w = half ? w_c : w_d;
  const int m0 = blockIdx.y * 64;
  const int b  = m0 >> 10;
  const int n0 = m0 & 1023;
  const int ctile = blockIdx.x;        // 0..35
  const int t = ctile / 12;            // 0=q 1=k 2=v
  const int h = ctile % 12;
  const size_t SZ = (size_t)BATCH * HEADS * NSEQ * HD;
  const size_t a_base = (size_t)b * (2048 * 768) + (size_t)(n0 + half * 1024) * 768;

  const int a_r = tid >> 2;
  const int a_k = (tid & 3) * 4;
  const int b_k = tid >> 4;
  const int b_c = (tid & 15) * 4;
  const int col0 = ctile * 64;
  const int tx = tid & 15;
  const int ty = tid >> 4;

  float acc[4][4] = {};
  for (int k0 = 0; k0 < 768; k0 += 16) {
    float4 av = *(const float4*)(x + a_base + (size_t)a_r * 768 + (k0 + a_k));
    float4 bv = *(const float4*)(w + (size_t)(k0 + b_k) * 2304 + (col0 + b_c));
    As[a_k + 0][a_r] = av.x;
    As[a_k + 1][a_r] = av.y;
    As[a_k + 2][a_r] = av.z;
    As[a_k + 3][a_r] = av.w;
    *(float4*)&Bs[b_k][b_c] = bv;
    __syncthreads();
#pragma unroll
    for (int kk = 0; kk < 16; ++kk) {
      float ar[4], br[4];
      *(float4*)ar = *(const float4*)&As[kk][ty * 4];
      *(float4*)br = *(const float4*)&Bs[kk][tx * 4];
#pragma unroll
      for (int i = 0; i < 4; ++i)
#pragma unroll
        for (int j = 0; j < 4; ++j)
          acc[i][j] += ar[i] * br[j];
    }
    __syncthreads();
  }

  unsigned short* hi_arr = ws + (size_t)(half * 6 + t * 2) * SZ;
  unsigned short* lo_arr = hi_arr + SZ;
  if (t < 2) {
    // row-major (B,H,N,64): rows n0+ty*4+i, cols tx*4+j
    size_t base = ((size_t)(b * HEADS + h) * NSEQ + n0 + ty * 4) * HD + tx * 4;
#pragma unroll
    for (int i = 0; i < 4; ++i) {
      unsigned short hv[4], lv[4];
#pragma unroll
      for (int j = 0; j < 4; ++j) split2(acc[i][j], hv[j], lv[j]);
      *(ushort4*)(hi_arr + base + (size_t)i * HD) = *(ushort4*)hv;
      *(ushort4*)(lo_arr + base + (size_t)i * HD) = *(ushort4*)lv;
    }
  } else {
    // transposed (B,H,64,N): row d=tx*4+j, cols n0+ty*4+i
    size_t base = ((size_t)(b * HEADS + h) * HD + tx * 4) * NSEQ + n0 + ty * 4;
#pragma unroll
    for (int j = 0; j < 4; ++j) {
      unsigned short hv[4], lv[4];
#pragma unroll
      for (int i = 0; i < 4; ++i) split2(acc[i][j], hv[i], lv[i]);
      *(ushort4*)(hi_arr + base + (size_t)j * NSEQ) = *(ushort4*)hv;
      *(ushort4*)(lo_arr + base + (size_t)j * NSEQ) = *(ushort4*)lv;
    }
  }
}

// ---------------------------------------------------------------------------
// Projection GEMM (fp32), standard fp32 (B,n,768) output. Used for step 6.
// ---------------------------------------------------------------------------
__global__ __launch_bounds__(256) void proj_gemm_k(
    const float* __restrict__ A,
    const float* __restrict__ W,
    const float* __restrict__ bias,
    float* __restrict__ out,
    long out_bstride, int n_off)
{
  __shared__ float As[16][68];
  __shared__ float Bs[16][64];
  const int tid = threadIdx.x;
  const int m0 = blockIdx.y * 64;
  const int b  = m0 >> 10;
  const int n0 = m0 & 1023;
  const int col0 = blockIdx.x * 64;

  const int a_r = tid >> 2;
  const int a_k = (tid & 3) * 4;
  const int b_k = tid >> 4;
  const int b_c = (tid & 15) * 4;
  const int tx = tid & 15;
  const int ty = tid >> 4;

  float acc[4][4] = {};
  for (int k0 = 0; k0 < 768; k0 += 16) {
    float4 av = *(const float4*)(A + (size_t)(m0 + a_r) * 768 + (k0 + a_k));
    float4 bv = *(const float4*)(W + (size_t)(k0 + b_k) * 768 + (col0 + b_c));
    As[a_k + 0][a_r] = av.x;
    As[a_k + 1][a_r] = av.y;
    As[a_k + 2][a_r] = av.z;
    As[a_k + 3][a_r] = av.w;
    *(float4*)&Bs[b_k][b_c] = bv;
    __syncthreads();
#pragma unroll
    for (int kk = 0; kk < 16; ++kk) {
      float ar[4], br[4];
      *(float4*)ar = *(const float4*)&As[kk][ty * 4];
      *(float4*)br = *(const float4*)&Bs[kk][tx * 4];
#pragma unroll
      for (int i = 0; i < 4; ++i)
#pragma unroll
        for (int j = 0; j < 4; ++j)
          acc[i][j] += ar[i] * br[j];
    }
    __syncthreads();
  }
  float* op = out + (size_t)b * out_bstride + (size_t)(n_off + n0) * 768 + col0;
#pragma unroll
  for (int i = 0; i < 4; ++i) {
    float4 o = make_float4(acc[i][0] + bias[col0 + tx * 4 + 0],
                           acc[i][1] + bias[col0 + tx * 4 + 1],
                           acc[i][2] + bias[col0 + tx * 4 + 2],
                           acc[i][3] + bias[col0 + tx * 4 + 3]);
    *(float4*)(op + (size_t)(ty * 4 + i) * 768 + tx * 4) = o;
  }
}

// ---------------------------------------------------------------------------
// Projection GEMM (fp32) -> transposed split-bf16 epilogue (B,H,64,N).
// blockIdx.x = head (64-col tile). Used for step 3 (output feeds attn-4 as V).
// ---------------------------------------------------------------------------
__global__ __launch_bounds__(256) void proj_gemm_vt_k(
    const float* __restrict__ A,
    const float* __restrict__ W,
    const float* __restrict__ bias,
    unsigned short* __restrict__ vt_hi,
    unsigned short* __restrict__ vt_lo)
{
  __shared__ float As[16][68];
  __shared__ float Bs[16][64];
  const int tid = threadIdx.x;
  const int m0 = blockIdx.y * 64;
  const int b  = m0 >> 10;
  const int n0 = m0 & 1023;
  const int h  = blockIdx.x;
  const int col0 = h * 64;

  const int a_r = tid >> 2;
  const int a_k = (tid & 3) * 4;
  const int b_k = tid >> 4;
  const int b_c = (tid & 15) * 4;
  const int tx = tid & 15;
  const int ty = tid >> 4;

  float acc[4][4] = {};
  for (int k0 = 0; k0 < 768; k0 += 16) {
    float4 av = *(const float4*)(A + (size_t)(m0 + a_r) * 768 + (k0 + a_k));
    float4 bv = *(const float4*)(W + (size_t)(k0 + b_k) * 768 + (col0 + b_c));
    As[a_k + 0][a_r] = av.x;
    As[a_k + 1][a_r] = av.y;
    As[a_k + 2][a_r] = av.z;
    As[a_k + 3][a_r] = av.w;
    *(float4*)&Bs[b_k][b_c] = bv;
    __syncthreads();
#pragma unroll
    for (int kk = 0; kk < 16; ++kk) {
      float ar[4], br[4];
      *(float4*)ar = *(const float4*)&As[kk][ty * 4];
      *(float4*)br = *(const float4*)&Bs[kk][tx * 4];
#pragma unroll
      for (int i = 0; i < 4; ++i)
#pragma unroll
        for (int j = 0; j < 4; ++j)
          acc[i][j] += ar[i] * br[j];
    }
    __syncthreads();
  }
  size_t base = ((size_t)(b * HEADS + h) * HD + tx * 4) * NSEQ + n0 + ty * 4;
#pragma unroll
  for (int j = 0; j < 4; ++j) {
    unsigned short hv[4], lv[4];
#pragma unroll
    for (int i = 0; i < 4; ++i) {
      float val = acc[i][j] + bias[col0 + tx * 4 + j];
      split2(val, hv[i], lv[i]);
    }
    *(ushort4*)(vt_hi + base + (size_t)j * NSEQ) = *(ushort4*)hv;
    *(ushort4*)(vt_lo + base + (size_t)j * NSEQ) = *(ushort4*)lv;
  }
}

// ---------------------------------------------------------------------------
// MFMA flash attention, split-bf16 (3-MFMA per product => ~fp32 accuracy).
// Block = 256 thr (4 waves); wave owns 16 q rows; Q-block = 64 rows.
// KV tiles of 64 staged in LDS: K hi/lo row-major [64][64], VT hi/lo [64][64]
// (kv-major cols), both with chunk^=(row&7) 16B swizzle (2-way max conflicts).
// S in 4x f32x4 C/D frags; softmax via 16-lane shfl_xor reductions; P packed
// (hi|lo<<16) into per-wave LDS [16][68] u32; PV reads P as A-frags.
// grid (16, 12, 4), out is fp32 (B, n, 768)-style with per-b stride.
// ---------------------------------------------------------------------------
__global__ __launch_bounds__(256) void attn_mfma_k(
    const unsigned short* __restrict__ q_hi, const unsigned short* __restrict__ q_lo,
    const unsigned short* __restrict__ k_hi, const unsigned short* __restrict__ k_lo,
    const unsigned short* __restrict__ vt_hi, const unsigned short* __restrict__ vt_lo,
    float* __restrict__ out, long o_bstride)
{
  __shared__ __attribute__((aligned(16))) unsigned char lds[50176];
  unsigned char* const ldsK_hi = lds;
  unsigned char* const ldsK_lo = lds + 8192;
  unsigned char* const ldsV_hi = lds + 16384;
  unsigned char* const ldsV_lo = lds + 24576;

  const int tid  = threadIdx.x;
  const int wave = tid >> 6;
  const int lane = tid & 63;
  const int b = blockIdx.z, h = blockIdx.y;
  const int bh = b * HEADS + h;
  const int q0 = blockIdx.x * 64 + wave * 16;

  unsigned int* const ldsP = (unsigned int*)(lds + 32768) + wave * (16 * 68);

  const int arow  = lane & 15;        // A-frag row / C-D col
  const int agrp  = lane >> 4;        // 0..3
  const int acol8 = agrp * 8;

  // Q fragments (hi/lo) for 2 k-steps of 32
  bf16x8 qh[2], ql[2];
  {
    const unsigned short* qp = q_hi + ((size_t)bh * NSEQ + q0 + arow) * HD + acol8;
    qh[0] = *(const bf16x8*)qp;
    qh[1] = *(const bf16x8*)(qp + 32);
    const unsigned short* qp2 = q_lo + ((size_t)bh * NSEQ + q0 + arow) * HD + acol8;
    ql[0] = *(const bf16x8*)qp2;
    ql[1] = *(const bf16x8*)(qp2 + 32);
  }

  f32x4 acc[4];
#pragma unroll
  for (int i = 0; i < 4; ++i) acc[i] = f32x4{0.f, 0.f, 0.f, 0.f};
  float m_run[4], l_run[4];
#pragma unroll
  for (int r = 0; r < 4; ++r) { m_run[r] = -3.0e38f; l_run[r] = 0.f; }

  const size_t kbase = (size_t)bh * NSEQ * HD;   // elements
  const size_t vbase = (size_t)bh * HD * NSEQ;

  for (int j0 = 0; j0 < NSEQ; j0 += 64) {
    __syncthreads();
    // ---- stage K/VT tiles (reg-staged; swizzled LDS writes) ----
    {
      const unsigned char* src0 = (const unsigned char*)k_hi  + (kbase + (size_t)j0 * HD) * 2;
      const unsigned char* src1 = (const unsigned char*)k_lo  + (kbase + (size_t)j0 * HD) * 2;
      const unsigned char* src2 = (const unsigned char*)vt_hi + (vbase + (size_t)j0) * 2;
      const unsigned char* src3 = (const unsigned char*)vt_lo + (vbase + (size_t)j0) * 2;
#pragma unroll
      for (int it = 0; it < 2; ++it) {
        const int idx = it * 256 + tid;          // 0..511
        const int r = idx >> 3, c = idx & 7;
        const int ldso = r * 128 + (((c ^ (r & 7)) << 4));
        u32x4v v0 = *(const u32x4v*)(src0 + (size_t)r * 128 + c * 16);
        u32x4v v1 = *(const u32x4v*)(src1 + (size_t)r * 128 + c * 16);
        u32x4v v2 = *(const u32x4v*)(src2 + (size_t)r * 2048 + c * 16);
        u32x4v v3 = *(const u32x4v*)(src3 + (size_t)r * 2048 + c * 16);
        *(u32x4v*)(ldsK_hi + ldso) = v0;
        *(u32x4v*)(ldsK_lo + ldso) = v1;
        *(u32x4v*)(ldsV_hi + ldso) = v2;
        *(u32x4v*)(ldsV_lo + ldso) = v3;
      }
    }
    __syncthreads();

    // ---- S = (Q K^T) * scale : 4 kv-subtiles of 16 ----
    f32x4 s[4];
#pragma unroll
    for (int nt = 0; nt < 4; ++nt) s[nt] = f32x4{0.f, 0.f, 0.f, 0.f};
#pragma unroll
    for (int ks = 0; ks < 2; ++ks) {
#pragma unroll
      for (int nt = 0; nt < 4; ++nt) {
        const int krow = nt * 16 + arow;
        const int chunk = ks * 4 + agrp;
        const int off = krow * 128 + (((chunk ^ (krow & 7)) << 4));
        bf16x8 bh_ = *(const bf16x8*)(ldsK_hi + off);
        bf16x8 bl_ = *(const bf16x8*)(ldsK_lo + off);
        s[nt] = __builtin_amdgcn_mfma_f32_16x16x32_bf16(qh[ks], bh_, s[nt], 0, 0, 0);
        s[nt] = __builtin_amdgcn_mfma_f32_16x16x32_bf16(qh[ks], bl_, s[nt], 0, 0, 0);
        s[nt] = __builtin_amdgcn_mfma_f32_16x16x32_bf16(ql[ks], bh_, s[nt], 0, 0, 0);
      }
    }
#pragma unroll
    for (int nt = 0; nt < 4; ++nt) s[nt] *= 0.125f;

    // ---- online softmax (row = (lane>>4)*4 + r, col = nt*16 + (lane&15)) ----
    float corr[4], rsum[4];
#pragma unroll
    for (int r = 0; r < 4; ++r) {
      float mx = fmaxf(fmaxf(s[0][r], s[1][r]), fmaxf(s[2][r], s[3][r]));
      mx = fmaxf(mx, __shfl_xor(mx, 1, 64));
      mx = fmaxf(mx, __shfl_xor(mx, 2, 64));
      mx = fmaxf(mx, __shfl_xor(mx, 4, 64));
      mx = fmaxf(mx, __shfl_xor(mx, 8, 64));
      float mnew = fmaxf(m_run[r], mx);
      corr[r] = __expf(m_run[r] - mnew);
      m_run[r] = mnew;
      rsum[r] = 0.f;
    }
#pragma unroll
    for (int nt = 0; nt < 4; ++nt) {
#pragma unroll
      for (int r = 0; r < 4; ++r) {
        float p = __expf(s[nt][r] - m_run[r]);
        rsum[r] += p;
        unsigned short ph, pl;
        split2(p, ph, pl);
        ldsP[(agrp * 4 + r) * 68 + nt * 16 + arow] =
            (unsigned int)ph | ((unsigned int)pl << 16);
      }
    }
#pragma unroll
    for (int r = 0; r < 4; ++r) {
      float sm = rsum[r];
      sm += __shfl_xor(sm, 1, 64);
      sm += __shfl_xor(sm, 2, 64);
      sm += __shfl_xor(sm, 4, 64);
      sm += __shfl_xor(sm, 8, 64);
      l_run[r] = l_run[r] * corr[r] + sm;
#pragma unroll
      for (int nt2 = 0; nt2 < 4; ++nt2) acc[nt2][r] *= corr[r];
    }

    // ---- O += P V : P A-frags from LDS, VT B-frags ----
#pragma unroll
    for (int kk = 0; kk < 2; ++kk) {
      const unsigned int* prow = ldsP + arow * 68 + kk * 32 + agrp * 8;
      u32x4v w0 = *(const u32x4v*)prow;
      u32x4v w1 = *(const u32x4v*)(prow + 4);
      bf16x8 pa_h, pa_l;
#pragma unroll
      for (int i = 0; i < 4; ++i) {
        pa_h[i]     = (short)(w0[i] & 0xffffu);
        pa_l[i]     = (short)(w0[i] >> 16);
        pa_h[4 + i] = (short)(w1[i] & 0xffffu);
        pa_l[4 + i] = (short)(w1[i] >> 16);
      }
#pragma unroll
      for (int nt2 = 0; nt2 < 4; ++nt2) {
        const int vrow = nt2 * 16 + arow;
        const int chunk = kk * 4 + agrp;
        const int off = vrow * 128 + (((chunk ^ (vrow & 7)) << 4));
        bf16x8 vh_ = *(const bf16x8*)(ldsV_hi + off);
        bf16x8 vl_ = *(const bf16x8*)(ldsV_lo + off);
        acc[nt2] = __builtin_amdgcn_mfma_f32_16x16x32_bf16(pa_h, vh_, acc[nt2], 0, 0, 0);
        acc[nt2] = __builtin_amdgcn_mfma_f32_16x16x32_bf16(pa_h, vl_, acc[nt2], 0, 0, 0);
        acc[nt2] = __builtin_amdgcn_mfma_f32_16x16x32_bf16(pa_l, vh_, acc[nt2], 0, 0, 0);
      }
    }
  }

  // ---- epilogue: O / l -> out fp32 ----
#pragma unroll
  for (int r = 0; r < 4; ++r) {
    const float inv = 1.f / l_run[r];
    const int n = q0 + agrp * 4 + r;
    float* rowp = out + (size_t)b * o_bstride + (size_t)n * C_DIM + h * HD + arow;
#pragma unroll
    for (int nt2 = 0; nt2 < 4; ++nt2)
      rowp[nt2 * 16] = acc[nt2][r] * inv;
  }
}

// ---------------------------------------------------------------------------
extern "C" void kernel_launch(void* const* d_in, const int* in_sizes, int n_in,
                              void* d_out, int out_size, void* d_ws, size_t ws_size,
                              hipStream_t stream)
{
  const float* x           = (const float*)d_in[0];
  const float* w_qkv_diff  = (const float*)d_in[1];
  const float* w_qkv_cond  = (const float*)d_in[2];
  const float* w_proj_diff = (const float*)d_in[3];
  const float* b_proj_diff = (const float*)d_in[4];
  const float* w_proj_cond = (const float*)d_in[5];
  const float* b_proj_cond = (const float*)d_in[6];
  float* out = (float*)d_out;

  const size_t SZ = (size_t)BATCH * HEADS * NSEQ * HD;  // 3145728
  unsigned short* sw = (unsigned short*)d_ws;
  // split arrays [12]: stream d: 0..5 = q_hi,q_lo,k_hi,k_lo,vt_hi,vt_lo; c: 6..11
  unsigned short* qd_hi  = sw + 0 * SZ;
  unsigned short* qd_lo  = sw + 1 * SZ;
  unsigned short* kd_hi  = sw + 2 * SZ;
  unsigned short* kd_lo  = sw + 3 * SZ;
  unsigned short* vtd_hi = sw + 4 * SZ;
  unsigned short* vtd_lo = sw + 5 * SZ;
  unsigned short* qc_hi  = sw + 6 * SZ;
  unsigned short* qc_lo  = sw + 7 * SZ;
  unsigned short* kc_hi  = sw + 8 * SZ;
  unsigned short* kc_lo  = sw + 9 * SZ;
  unsigned short* vtc_hi = sw + 10 * SZ;
  unsigned short* vtc_lo = sw + 11 * SZ;
  float* o_attn = (float*)((char*)d_ws + 12 * SZ * 2);  // fp32 (B,N,C), 12.58MB
  // vt2 (proj_diff output, transposed split) reuses q_d slots (dead after attn-2)
  unsigned short* vt2_hi = qd_hi;
  unsigned short* vt2_lo = qd_lo;

  // 1. QKV projections, both streams
  qkv_gemm_split_k<<<dim3(36, 64, 2), 256, 0, stream>>>(x, w_qkv_diff, w_qkv_cond, sw);

  // 2. attn_diff(q_d,k_d,v_d) -> o_attn (B,N,C)
  attn_mfma_k<<<dim3(16, 12, 4), 256, 0, stream>>>(
      qd_hi, qd_lo, kd_hi, kd_lo, vtd_hi, vtd_lo, o_attn, (long)NSEQ * C_DIM);

  // 3. (o_attn @ w_proj_diff + b) -> vt2 transposed split
  proj_gemm_vt_k<<<dim3(12, 64), 256, 0, stream>>>(
      o_attn, w_proj_diff, b_proj_diff, vt2_hi, vt2_lo);

  // 4. attn_cond(q_c,k_c, vt2) -> out[:, :N]
  attn_mfma_k<<<dim3(16, 12, 4), 256, 0, stream>>>(
      qc_hi, qc_lo, kc_hi, kc_lo, vt2_hi, vt2_lo, out, (long)2048 * C_DIM);

  // 5. attn_cond(q_c,k_c,v_c) -> o_attn (B,N,C)  (o_attn reusable now)
  attn_mfma_k<<<dim3(16, 12, 4), 256, 0, stream>>>(
      qc_hi, qc_lo, kc_hi, kc_lo, vtc_hi, vtc_lo, o_attn, (long)NSEQ * C_DIM);

  // 6. out[:, N:] = o_attn @ w_proj_cond + b
  proj_gemm_k<<<dim3(12, 64), 256, 0, stream>>>(
      o_attn, w_proj_cond, b_proj_cond, out, (long)2048 * C_DIM, 1024);
}

// Round 3
// 457.385 us; speedup vs baseline: 6.9550x; 1.9194x over previous
//
#include <hip/hip_runtime.h>
#include <hip/hip_bf16.h>

// B=4, N0=2048 (N=1024 diff + 1024 cond), C=768, H=12, hd=64. All fp32 I/O.
// All GEMMs + attention on MFMA via split-bf16 (x = hi + lo, 3 bf16-MFMA terms
// per product => ~fp32 accuracy).
//   0. weight prep: wT[n][k] split hi/lo for all 4 weight matrices
//   1. qkv both streams  [MFMA] -> split q/k (B,H,N,64) + vt (B,H,64,N) hi/lo
//   2. osp = attn(q_d,k_d,vt_d)              [MFMA] -> fp32 (B*N,768)
//   3. vt2 = (osp @ w_proj_diff + b)^T split [MFMA] -> (B,H,64,N) hi/lo
//   4. out[:, :N] = attn(q_c,k_c, vt2)       [MFMA]
//   5. osp = attn(q_c,k_c,vt_c)              [MFMA]
//   6. out[:, N:] = osp @ w_proj_cond + b    [MFMA]

#define C_DIM 768
#define HEADS 12
#define HD 64
#define NSEQ 1024
#define BATCH 4
#define SZC 3145728  // BATCH*HEADS*NSEQ*HD

typedef short bf16x8 __attribute__((ext_vector_type(8)));
typedef float f32x4 __attribute__((ext_vector_type(4)));
typedef unsigned int u32x4v __attribute__((ext_vector_type(4)));

__device__ __forceinline__ unsigned short f2bf(float x) {
  __hip_bfloat16 h = __float2bfloat16(x);
  return *reinterpret_cast<unsigned short*>(&h);
}
__device__ __forceinline__ float bf2f(unsigned short u) {
  __hip_bfloat16 h = *reinterpret_cast<__hip_bfloat16*>(&u);
  return __bfloat162float(h);
}
__device__ __forceinline__ void split2(float x, unsigned short& hi, unsigned short& lo) {
  unsigned short h = f2bf(x);
  lo = f2bf(x - bf2f(h));
  hi = h;
}

// ---------------------------------------------------------------------------
// Weight prep: w (K x N fp32, row-major) -> wT hi/lo (N x K bf16 split).
// 32x32 LDS tile transpose, coalesced both sides. Block (32,8).
// ---------------------------------------------------------------------------
__global__ __launch_bounds__(256) void split_wT_k(
    const float* __restrict__ w, int K, int N,
    unsigned short* __restrict__ th, unsigned short* __restrict__ tl)
{
  __shared__ float T[32][33];
  const int n0 = blockIdx.x * 32, k0 = blockIdx.y * 32;
  const int tx = threadIdx.x, ty = threadIdx.y;
#pragma unroll
  for (int i = 0; i < 4; ++i) {
    int k = ty + i * 8;
    T[k][tx] = w[(size_t)(k0 + k) * N + n0 + tx];
  }
  __syncthreads();
#pragma unroll
  for (int i = 0; i < 4; ++i) {
    int n = ty + i * 8;
    float v = T[tx][n];
    unsigned short hi, lo;
    split2(v, hi, lo);
    th[(size_t)(n0 + n) * K + k0 + tx] = hi;
    tl[(size_t)(n0 + n) * K + k0 + tx] = lo;
  }
}

// ---------------------------------------------------------------------------
// Unified split-bf16 MFMA GEMM: C = A(fp32, ld=768) x B(768 x Ncols, via
// pre-split B^T bf16 hi/lo, ld=768). 128x128 tile, BK=32, 256 thr = 4 waves,
// wave = 64x64 (4x4 frags of 16x16x32). A split hi/lo during LDS staging.
// LDS rows padded to 80B -> <=2-way bank conflicts.
// EPI 0: qkv  -> ws split arrays (q/k row-major, v transposed), grid.z=half
// EPI 1: proj -> fp32 d_out[:, N:] + bias
// EPI 2: proj -> vt2 transposed split + bias
// ---------------------------------------------------------------------------
template <int EPI>
__global__ __launch_bounds__(256) void gemm_mfma_k(
    const float* __restrict__ A,
    const unsigned short* __restrict__ BTh0, const unsigned short* __restrict__ BTl0,
    const unsigned short* __restrict__ BTh1, const unsigned short* __restrict__ BTl1,
    const float* __restrict__ bias,
    unsigned short* __restrict__ ws_split,   // EPI0
    float* __restrict__ outf,                // EPI1
    unsigned short* __restrict__ vt_hi,      // EPI2
    unsigned short* __restrict__ vt_lo)
{
  __shared__ __attribute__((aligned(16))) unsigned short lds[20480];  // 40 KB
  unsigned short* const lAh = lds;            // [128][40] ushort (80B rows)
  unsigned short* const lAl = lds + 5120;
  unsigned short* const lBh = lds + 10240;
  unsigned short* const lBl = lds + 15360;

  const int tid = threadIdx.x;
  const int lane = tid & 63;
  const int wave = tid >> 6;
  const int wr = wave >> 1, wc = wave & 1;
  const int arow = lane & 15;
  const int agrp = lane >> 4;

  const int m0 = blockIdx.y * 128;
  const int b = m0 >> 10;
  const int nloc = m0 & 1023;
  const int half = blockIdx.z;
  const int c0 = blockIdx.x * 128;

  const float* Abase = A + (size_t)(EPI == 0 ? (b * 2048 + half * 1024 + nloc) : m0) * 768;
  const unsigned short* BTh = (EPI == 0 && half) ? BTh1 : BTh0;
  const unsigned short* BTl = (EPI == 0 && half) ? BTl1 : BTl0;

  f32x4 acc[4][4];
#pragma unroll
  for (int i = 0; i < 4; ++i)
#pragma unroll
    for (int j = 0; j < 4; ++j) acc[i][j] = f32x4{0.f, 0.f, 0.f, 0.f};

  for (int k0 = 0; k0 < 768; k0 += 32) {
    __syncthreads();
    // ---- stage A (fp32 -> split hi/lo) ----
#pragma unroll
    for (int it = 0; it < 2; ++it) {
      const int idx = it * 256 + tid;        // 0..511
      const int r = idx >> 2, c = idx & 3;
      const float* p = Abase + (size_t)r * 768 + k0 + c * 8;
      float4 f0 = *(const float4*)p;
      float4 f1 = *(const float4*)(p + 4);
      float fa[8] = {f0.x, f0.y, f0.z, f0.w, f1.x, f1.y, f1.z, f1.w};
      unsigned short hv[8], lv[8];
#pragma unroll
      for (int j = 0; j < 8; ++j) split2(fa[j], hv[j], lv[j]);
      const int off = r * 40 + c * 8;
      *(u32x4v*)(lAh + off) = *(u32x4v*)hv;
      *(u32x4v*)(lAl + off) = *(u32x4v*)lv;
    }
    // ---- stage B (pre-split bf16) ----
#pragma unroll
    for (int it = 0; it < 4; ++it) {
      const int idx = it * 256 + tid;        // 0..1023
      const int arr = idx >> 9;              // 0 hi, 1 lo
      const int ci = idx & 511;
      const int r = ci >> 2, c = ci & 3;
      const unsigned short* p = (arr ? BTl : BTh) + (size_t)(c0 + r) * 768 + k0 + c * 8;
      u32x4v v = *(const u32x4v*)p;
      *(u32x4v*)((arr ? lBl : lBh) + r * 40 + c * 8) = v;
    }
    __syncthreads();

    // ---- fragments + 48 MFMAs ----
    bf16x8 ah[4], al[4], bhf[4], blf[4];
#pragma unroll
    for (int mf = 0; mf < 4; ++mf) {
      const int off = (wr * 64 + mf * 16 + arow) * 40 + agrp * 8;
      ah[mf] = *(const bf16x8*)(lAh + off);
      al[mf] = *(const bf16x8*)(lAl + off);
    }
#pragma unroll
    for (int nf = 0; nf < 4; ++nf) {
      const int off = (wc * 64 + nf * 16 + arow) * 40 + agrp * 8;
      bhf[nf] = *(const bf16x8*)(lBh + off);
      blf[nf] = *(const bf16x8*)(lBl + off);
    }
#pragma unroll
    for (int mf = 0; mf < 4; ++mf)
#pragma unroll
      for (int nf = 0; nf < 4; ++nf) {
        acc[mf][nf] = __builtin_amdgcn_mfma_f32_16x16x32_bf16(ah[mf], bhf[nf], acc[mf][nf], 0, 0, 0);
        acc[mf][nf] = __builtin_amdgcn_mfma_f32_16x16x32_bf16(ah[mf], blf[nf], acc[mf][nf], 0, 0, 0);
        acc[mf][nf] = __builtin_amdgcn_mfma_f32_16x16x32_bf16(al[mf], bhf[nf], acc[mf][nf], 0, 0, 0);
      }
  }

  // ---- epilogues ----
  if constexpr (EPI == 0) {
#pragma unroll
    for (int nf = 0; nf < 4; ++nf) {
      const int cg = c0 + wc * 64 + nf * 16 + arow;
      const int t = cg / 768;
      const int rem = cg - t * 768;
      const int h = rem >> 6;
      const int d = rem & 63;
      unsigned short* hi_arr = ws_split + (size_t)(half * 6 + t * 2) * SZC;
      unsigned short* lo_arr = hi_arr + SZC;
      const size_t bh_ = (size_t)(b * HEADS + h);
#pragma unroll
      for (int mf = 0; mf < 4; ++mf) {
#pragma unroll
        for (int ri = 0; ri < 4; ++ri) {
          const int n = nloc + wr * 64 + mf * 16 + agrp * 4 + ri;
          unsigned short hi, lo;
          split2(acc[mf][nf][ri], hi, lo);
          size_t idx;
          if (t < 2) idx = (bh_ * NSEQ + n) * HD + d;
          else       idx = (bh_ * HD + d) * NSEQ + n;
          hi_arr[idx] = hi;
          lo_arr[idx] = lo;
        }
      }
    }
  } else if constexpr (EPI == 1) {
#pragma unroll
    for (int nf = 0; nf < 4; ++nf) {
      const int cg = c0 + wc * 64 + nf * 16 + arow;
      const float bv = bias[cg];
#pragma unroll
      for (int mf = 0; mf < 4; ++mf) {
#pragma unroll
        for (int ri = 0; ri < 4; ++ri) {
          const int m = m0 + wr * 64 + mf * 16 + agrp * 4 + ri;
          const int bb = m >> 10, n = m & 1023;
          outf[(size_t)bb * (2048 * 768) + (size_t)(1024 + n) * 768 + cg] =
              acc[mf][nf][ri] + bv;
        }
      }
    }
  } else {  // EPI == 2
#pragma unroll
    for (int nf = 0; nf < 4; ++nf) {
      const int cg = c0 + wc * 64 + nf * 16 + arow;   // 0..767
      const int h = cg >> 6, d = cg & 63;
      const float bv = bias[cg];
#pragma unroll
      for (int mf = 0; mf < 4; ++mf) {
#pragma unroll
        for (int ri = 0; ri < 4; ++ri) {
          const int m = m0 + wr * 64 + mf * 16 + agrp * 4 + ri;
          const int bb = m >> 10, n = m & 1023;
          unsigned short hi, lo;
          split2(acc[mf][nf][ri] + bv, hi, lo);
          const size_t idx = ((size_t)(bb * HEADS + h) * HD + d) * NSEQ + n;
          vt_hi[idx] = hi;
          vt_lo[idx] = lo;
        }
      }
    }
  }
}

// ---------------------------------------------------------------------------
// MFMA flash attention, split-bf16 (unchanged from R2 — proven).
// Block = 256 thr (4 waves); wave owns 16 q rows; KV tiles of 64 in swizzled
// LDS; online softmax; P split-packed through per-wave LDS into A-frags.
// grid (16, 12, 4); out fp32 (B, n, 768)-style with per-b stride.
// ---------------------------------------------------------------------------
__global__ __launch_bounds__(256) void attn_mfma_k(
    const unsigned short* __restrict__ q_hi, const unsigned short* __restrict__ q_lo,
    const unsigned short* __restrict__ k_hi, const unsigned short* __restrict__ k_lo,
    const unsigned short* __restrict__ vt_hi, const unsigned short* __restrict__ vt_lo,
    float* __restrict__ out, long o_bstride)
{
  __shared__ __attribute__((aligned(16))) unsigned char lds[50176];
  unsigned char* const ldsK_hi = lds;
  unsigned char* const ldsK_lo = lds + 8192;
  unsigned char* const ldsV_hi = lds + 16384;
  unsigned char* const ldsV_lo = lds + 24576;

  const int tid  = threadIdx.x;
  const int wave = tid >> 6;
  const int lane = tid & 63;
  const int b = blockIdx.z, h = blockIdx.y;
  const int bh = b * HEADS + h;
  const int q0 = blockIdx.x * 64 + wave * 16;

  unsigned int* const ldsP = (unsigned int*)(lds + 32768) + wave * (16 * 68);

  const int arow  = lane & 15;
  const int agrp  = lane >> 4;
  const int acol8 = agrp * 8;

  bf16x8 qh[2], ql[2];
  {
    const unsigned short* qp = q_hi + ((size_t)bh * NSEQ + q0 + arow) * HD + acol8;
    qh[0] = *(const bf16x8*)qp;
    qh[1] = *(const bf16x8*)(qp + 32);
    const unsigned short* qp2 = q_lo + ((size_t)bh * NSEQ + q0 + arow) * HD + acol8;
    ql[0] = *(const bf16x8*)qp2;
    ql[1] = *(const bf16x8*)(qp2 + 32);
  }

  f32x4 acc[4];
#pragma unroll
  for (int i = 0; i < 4; ++i) acc[i] = f32x4{0.f, 0.f, 0.f, 0.f};
  float m_run[4], l_run[4];
#pragma unroll
  for (int r = 0; r < 4; ++r) { m_run[r] = -3.0e38f; l_run[r] = 0.f; }

  const size_t kbase = (size_t)bh * NSEQ * HD;
  const size_t vbase = (size_t)bh * HD * NSEQ;

  for (int j0 = 0; j0 < NSEQ; j0 += 64) {
    __syncthreads();
    {
      const unsigned char* src0 = (const unsigned char*)k_hi  + (kbase + (size_t)j0 * HD) * 2;
      const unsigned char* src1 = (const unsigned char*)k_lo  + (kbase + (size_t)j0 * HD) * 2;
      const unsigned char* src2 = (const unsigned char*)vt_hi + (vbase + (size_t)j0) * 2;
      const unsigned char* src3 = (const unsigned char*)vt_lo + (vbase + (size_t)j0) * 2;
#pragma unroll
      for (int it = 0; it < 2; ++it) {
        const int idx = it * 256 + tid;
        const int r = idx >> 3, c = idx & 7;
        const int ldso = r * 128 + (((c ^ (r & 7)) << 4));
        u32x4v v0 = *(const u32x4v*)(src0 + (size_t)r * 128 + c * 16);
        u32x4v v1 = *(const u32x4v*)(src1 + (size_t)r * 128 + c * 16);
        u32x4v v2 = *(const u32x4v*)(src2 + (size_t)r * 2048 + c * 16);
        u32x4v v3 = *(const u32x4v*)(src3 + (size_t)r * 2048 + c * 16);
        *(u32x4v*)(ldsK_hi + ldso) = v0;
        *(u32x4v*)(ldsK_lo + ldso) = v1;
        *(u32x4v*)(ldsV_hi + ldso) = v2;
        *(u32x4v*)(ldsV_lo + ldso) = v3;
      }
    }
    __syncthreads();

    f32x4 s[4];
#pragma unroll
    for (int nt = 0; nt < 4; ++nt) s[nt] = f32x4{0.f, 0.f, 0.f, 0.f};
#pragma unroll
    for (int ks = 0; ks < 2; ++ks) {
#pragma unroll
      for (int nt = 0; nt < 4; ++nt) {
        const int krow = nt * 16 + arow;
        const int chunk = ks * 4 + agrp;
        const int off = krow * 128 + (((chunk ^ (krow & 7)) << 4));
        bf16x8 bh_ = *(const bf16x8*)(ldsK_hi + off);
        bf16x8 bl_ = *(const bf16x8*)(ldsK_lo + off);
        s[nt] = __builtin_amdgcn_mfma_f32_16x16x32_bf16(qh[ks], bh_, s[nt], 0, 0, 0);
        s[nt] = __builtin_amdgcn_mfma_f32_16x16x32_bf16(qh[ks], bl_, s[nt], 0, 0, 0);
        s[nt] = __builtin_amdgcn_mfma_f32_16x16x32_bf16(ql[ks], bh_, s[nt], 0, 0, 0);
      }
    }
#pragma unroll
    for (int nt = 0; nt < 4; ++nt) s[nt] *= 0.125f;

    float corr[4], rsum[4];
#pragma unroll
    for (int r = 0; r < 4; ++r) {
      float mx = fmaxf(fmaxf(s[0][r], s[1][r]), fmaxf(s[2][r], s[3][r]));
      mx = fmaxf(mx, __shfl_xor(mx, 1, 64));
      mx = fmaxf(mx, __shfl_xor(mx, 2, 64));
      mx = fmaxf(mx, __shfl_xor(mx, 4, 64));
      mx = fmaxf(mx, __shfl_xor(mx, 8, 64));
      float mnew = fmaxf(m_run[r], mx);
      corr[r] = __expf(m_run[r] - mnew);
      m_run[r] = mnew;
      rsum[r] = 0.f;
    }
#pragma unroll
    for (int nt = 0; nt < 4; ++nt) {
#pragma unroll
      for (int r = 0; r < 4; ++r) {
        float p = __expf(s[nt][r] - m_run[r]);
        rsum[r] += p;
        unsigned short ph, pl;
        split2(p, ph, pl);
        ldsP[(agrp * 4 + r) * 68 + nt * 16 + arow] =
            (unsigned int)ph | ((unsigned int)pl << 16);
      }
    }
#pragma unroll
    for (int r = 0; r < 4; ++r) {
      float sm = rsum[r];
      sm += __shfl_xor(sm, 1, 64);
      sm += __shfl_xor(sm, 2, 64);
      sm += __shfl_xor(sm, 4, 64);
      sm += __shfl_xor(sm, 8, 64);
      l_run[r] = l_run[r] * corr[r] + sm;
#pragma unroll
      for (int nt2 = 0; nt2 < 4; ++nt2) acc[nt2][r] *= corr[r];
    }

#pragma unroll
    for (int kk = 0; kk < 2; ++kk) {
      const unsigned int* prow = ldsP + arow * 68 + kk * 32 + agrp * 8;
      u32x4v w0 = *(const u32x4v*)prow;
      u32x4v w1 = *(const u32x4v*)(prow + 4);
      bf16x8 pa_h, pa_l;
#pragma unroll
      for (int i = 0; i < 4; ++i) {
        pa_h[i]     = (short)(w0[i] & 0xffffu);
        pa_l[i]     = (short)(w0[i] >> 16);
        pa_h[4 + i] = (short)(w1[i] & 0xffffu);
        pa_l[4 + i] = (short)(w1[i] >> 16);
      }
#pragma unroll
      for (int nt2 = 0; nt2 < 4; ++nt2) {
        const int vrow = nt2 * 16 + arow;
        const int chunk = kk * 4 + agrp;
        const int off = vrow * 128 + (((chunk ^ (vrow & 7)) << 4));
        bf16x8 vh_ = *(const bf16x8*)(ldsV_hi + off);
        bf16x8 vl_ = *(const bf16x8*)(ldsV_lo + off);
        acc[nt2] = __builtin_amdgcn_mfma_f32_16x16x32_bf16(pa_h, vh_, acc[nt2], 0, 0, 0);
        acc[nt2] = __builtin_amdgcn_mfma_f32_16x16x32_bf16(pa_h, vl_, acc[nt2], 0, 0, 0);
        acc[nt2] = __builtin_amdgcn_mfma_f32_16x16x32_bf16(pa_l, vh_, acc[nt2], 0, 0, 0);
      }
    }
  }

#pragma unroll
  for (int r = 0; r < 4; ++r) {
    const float inv = 1.f / l_run[r];
    const int n = q0 + agrp * 4 + r;
    float* rowp = out + (size_t)b * o_bstride + (size_t)n * C_DIM + h * HD + arow;
#pragma unroll
    for (int nt2 = 0; nt2 < 4; ++nt2)
      rowp[nt2 * 16] = acc[nt2][r] * inv;
  }
}

// ---------------------------------------------------------------------------
extern "C" void kernel_launch(void* const* d_in, const int* in_sizes, int n_in,
                              void* d_out, int out_size, void* d_ws, size_t ws_size,
                              hipStream_t stream)
{
  const float* x           = (const float*)d_in[0];
  const float* w_qkv_diff  = (const float*)d_in[1];
  const float* w_qkv_cond  = (const float*)d_in[2];
  const float* w_proj_diff = (const float*)d_in[3];
  const float* b_proj_diff = (const float*)d_in[4];
  const float* w_proj_cond = (const float*)d_in[5];
  const float* b_proj_cond = (const float*)d_in[6];
  float* out = (float*)d_out;

  const size_t SZ = SZC;                  // 3145728
  const size_t WQ = 2304 * 768;           // 1769472
  const size_t WP = 768 * 768;            // 589824
  unsigned short* sw = (unsigned short*)d_ws;
  // [0..12SZ): qkv split arrays: per stream q_hi,q_lo,k_hi,k_lo,vt_hi,vt_lo
  unsigned short* qd_hi  = sw + 0 * SZ;
  unsigned short* qd_lo  = sw + 1 * SZ;
  unsigned short* kd_hi  = sw + 2 * SZ;
  unsigned short* kd_lo  = sw + 3 * SZ;
  unsigned short* vtd_hi = sw + 4 * SZ;
  unsigned short* vtd_lo = sw + 5 * SZ;
  unsigned short* qc_hi  = sw + 6 * SZ;
  unsigned short* qc_lo  = sw + 7 * SZ;
  unsigned short* kc_hi  = sw + 8 * SZ;
  unsigned short* kc_lo  = sw + 9 * SZ;
  unsigned short* vtc_hi = sw + 10 * SZ;
  unsigned short* vtc_lo = sw + 11 * SZ;
  // [12SZ..): transposed split weights
  unsigned short* wqdT_h = sw + 12 * SZ;
  unsigned short* wqdT_l = wqdT_h + WQ;
  unsigned short* wqcT_h = wqdT_l + WQ;
  unsigned short* wqcT_l = wqcT_h + WQ;
  unsigned short* wpdT_h = wqcT_l + WQ;
  unsigned short* wpdT_l = wpdT_h + WP;
  unsigned short* wpcT_h = wpdT_l + WP;
  unsigned short* wpcT_l = wpcT_h + WP;
  // total: 12*SZ + 4*WQ + 4*WP ushorts = 94.4 MB
  // osp (fp32, 4096x768) aliases wqkvT_d+wqkvT_c (dead after qkv GEMM)
  float* osp = (float*)(sw + 12 * SZ);
  // vt2 aliases q_d (dead after attn step 2)
  unsigned short* vt2_hi = qd_hi;
  unsigned short* vt2_lo = qd_lo;

  // 0. weight prep
  split_wT_k<<<dim3(72, 24), dim3(32, 8), 0, stream>>>(w_qkv_diff, 768, 2304, wqdT_h, wqdT_l);
  split_wT_k<<<dim3(72, 24), dim3(32, 8), 0, stream>>>(w_qkv_cond, 768, 2304, wqcT_h, wqcT_l);
  split_wT_k<<<dim3(24, 24), dim3(32, 8), 0, stream>>>(w_proj_diff, 768, 768, wpdT_h, wpdT_l);
  split_wT_k<<<dim3(24, 24), dim3(32, 8), 0, stream>>>(w_proj_cond, 768, 768, wpcT_h, wpcT_l);

  // 1. qkv both streams -> split arrays
  gemm_mfma_k<0><<<dim3(18, 32, 2), 256, 0, stream>>>(
      x, wqdT_h, wqdT_l, wqcT_h, wqcT_l, nullptr, sw, nullptr, nullptr, nullptr);

  // 2. attn_diff -> osp fp32 (B*N, 768)
  attn_mfma_k<<<dim3(16, 12, 4), 256, 0, stream>>>(
      qd_hi, qd_lo, kd_hi, kd_lo, vtd_hi, vtd_lo, osp, (long)NSEQ * C_DIM);

  // 3. (osp @ w_proj_diff + b)^T split -> vt2
  gemm_mfma_k<2><<<dim3(6, 32, 1), 256, 0, stream>>>(
      osp, wpdT_h, wpdT_l, nullptr, nullptr, b_proj_diff, nullptr, nullptr, vt2_hi, vt2_lo);

  // 4. attn_cond(q_c,k_c, vt2) -> out[:, :N]
  attn_mfma_k<<<dim3(16, 12, 4), 256, 0, stream>>>(
      qc_hi, qc_lo, kc_hi, kc_lo, vt2_hi, vt2_lo, out, (long)2048 * C_DIM);

  // 5. attn_cond(q_c,k_c, vt_c) -> osp
  attn_mfma_k<<<dim3(16, 12, 4), 256, 0, stream>>>(
      qc_hi, qc_lo, kc_hi, kc_lo, vtc_hi, vtc_lo, osp, (long)NSEQ * C_DIM);

  // 6. out[:, N:] = osp @ w_proj_cond + b
  gemm_mfma_k<1><<<dim3(6, 32, 1), 256, 0, stream>>>(
      osp, wpcT_h, wpcT_l, nullptr, nullptr, b_proj_cond, nullptr, out, nullptr, nullptr);
}

// Round 4
// 394.109 us; speedup vs baseline: 8.0716x; 1.1606x over previous
//
#include <hip/hip_runtime.h>
#include <hip/hip_bf16.h>

// B=4, N0=2048 (N=1024 diff + 1024 cond), C=768, H=12, hd=64. All fp32 I/O.
// Split-bf16 (x = hi + lo, 3 bf16-MFMA terms) for all GEMM/attention math.
//   0. weight prep: wT[n][k] split hi/lo for all 4 weight matrices
//   1. qkv both streams  [MFMA] -> split q/k (B,H,N,64) + vt (B,H,64,N) hi/lo
//   2. osp = attn(q_d,k_d,vt_d)              [MFMA] -> SPLIT (B*N,768) hi/lo
//   3. vt2 = (osp @ w_proj_diff + b)^T split [MFMA] -> (B,H,64,N) hi/lo
//   4+5 fused: P = softmax(q_c k_c^T) once;
//        out[:, :N] = P @ vt2 (fp32), osp = P @ vt_c (split)
//   6. out[:, N:] = osp @ w_proj_cond + b    [MFMA]

#define C_DIM 768
#define HEADS 12
#define HD 64
#define NSEQ 1024
#define BATCH 4
#define SZC 3145728  // BATCH*HEADS*NSEQ*HD

typedef short bf16x8 __attribute__((ext_vector_type(8)));
typedef float f32x4 __attribute__((ext_vector_type(4)));
typedef unsigned int u32x4v __attribute__((ext_vector_type(4)));

typedef __attribute__((address_space(3))) unsigned int lds_u32_t;
typedef __attribute__((address_space(1))) const unsigned int glb_u32_t;

__device__ __forceinline__ void gl16(const void* g, void* l) {
  __builtin_amdgcn_global_load_lds((glb_u32_t*)g, (lds_u32_t*)l, 16, 0, 0);
}

__device__ __forceinline__ unsigned short f2bf(float x) {
  __hip_bfloat16 h = __float2bfloat16(x);
  return *reinterpret_cast<unsigned short*>(&h);
}
__device__ __forceinline__ float bf2f(unsigned short u) {
  __hip_bfloat16 h = *reinterpret_cast<__hip_bfloat16*>(&u);
  return __bfloat162float(h);
}
__device__ __forceinline__ void split2(float x, unsigned short& hi, unsigned short& lo) {
  unsigned short h = f2bf(x);
  lo = f2bf(x - bf2f(h));
  hi = h;
}

// ---------------------------------------------------------------------------
// Weight prep: w (K x N fp32, row-major) -> wT hi/lo (N x K bf16 split).
// ---------------------------------------------------------------------------
__global__ __launch_bounds__(256) void split_wT_k(
    const float* __restrict__ w, int K, int N,
    unsigned short* __restrict__ th, unsigned short* __restrict__ tl)
{
  __shared__ float T[32][33];
  const int n0 = blockIdx.x * 32, k0 = blockIdx.y * 32;
  const int tx = threadIdx.x, ty = threadIdx.y;
#pragma unroll
  for (int i = 0; i < 4; ++i) {
    int k = ty + i * 8;
    T[k][tx] = w[(size_t)(k0 + k) * N + n0 + tx];
  }
  __syncthreads();
#pragma unroll
  for (int i = 0; i < 4; ++i) {
    int n = ty + i * 8;
    float v = T[tx][n];
    unsigned short hi, lo;
    split2(v, hi, lo);
    th[(size_t)(n0 + n) * K + k0 + tx] = hi;
    tl[(size_t)(n0 + n) * K + k0 + tx] = lo;
  }
}

// ---------------------------------------------------------------------------
// QKV GEMM: A = x fp32 (reg-split staging, prefetched), B = pre-split weights
// via global_load_lds into linear [128][32]us tiles. 128x128 tile, BK=32,
// 4 waves. Epilogue scatters split q/k row-major + v transposed.
// ---------------------------------------------------------------------------
__global__ __launch_bounds__(256) void qkv_gemm_k(
    const float* __restrict__ x,
    const unsigned short* __restrict__ wdh, const unsigned short* __restrict__ wdl,
    const unsigned short* __restrict__ wch, const unsigned short* __restrict__ wcl,
    unsigned short* __restrict__ ws_split)
{
  __shared__ __attribute__((aligned(16))) unsigned short lds[18432];  // 36 KB
  unsigned short* const lAh = lds;           // [128][40] (80B rows, padded)
  unsigned short* const lAl = lds + 5120;
  unsigned short* const lBh = lds + 10240;   // [128][32] linear (gload_lds)
  unsigned short* const lBl = lds + 14336;

  const int tid = threadIdx.x;
  const int lane = tid & 63;
  const int wave = tid >> 6;
  const int wr = wave >> 1, wc = wave & 1;
  const int arow = lane & 15, agrp = lane >> 4;

  // XCD-aware bijective swizzle: nwg = 18*32*2 = 1152, 1152/8 = 144
  int flat = blockIdx.x + 18 * blockIdx.y + 576 * blockIdx.z;
  flat = (flat & 7) * 144 + (flat >> 3);
  const int bx = flat % 18;
  const int by = (flat / 18) & 31;
  const int half = flat / 576;

  const int m0 = by * 128;
  const int b = m0 >> 10, nloc = m0 & 1023;
  const int c0 = bx * 128;
  const unsigned short* __restrict__ BTh = half ? wch : wdh;
  const unsigned short* __restrict__ BTl = half ? wcl : wdl;
  const float* __restrict__ Abase = x + (size_t)(b * 2048 + half * 1024 + nloc) * 768;

  // B gload lanes: r = tid>>2 (64 rows/call), c = tid&3 (16B chunks)
  const unsigned short* gBh = BTh + (size_t)(c0 + (tid >> 2)) * 768 + (tid & 3) * 8;
  const unsigned short* gBl = BTl + (size_t)(c0 + (tid >> 2)) * 768 + (tid & 3) * 8;
  unsigned short* const lBh_w = lBh + (wave * 16) * 32;  // wave-uniform dest
  unsigned short* const lBl_w = lBl + (wave * 16) * 32;

  const int ar_ = tid >> 2, ac_ = tid & 3;   // A lanes: 2 its x 64 rows

  f32x4 acc[4][4];
#pragma unroll
  for (int i = 0; i < 4; ++i)
#pragma unroll
    for (int j = 0; j < 4; ++j) acc[i][j] = f32x4{0.f, 0.f, 0.f, 0.f};

  // prefetch+split A for k0 = 0
  bf16x8 pAh[2], pAl[2];
#pragma unroll
  for (int it = 0; it < 2; ++it) {
    const float* p = Abase + (size_t)(it * 64 + ar_) * 768 + ac_ * 8;
    float4 f0 = *(const float4*)p;
    float4 f1 = *(const float4*)(p + 4);
    float fa[8] = {f0.x, f0.y, f0.z, f0.w, f1.x, f1.y, f1.z, f1.w};
#pragma unroll
    for (int j = 0; j < 8; ++j) {
      unsigned short hi, lo;
      split2(fa[j], hi, lo);
      pAh[it][j] = (short)hi; pAl[it][j] = (short)lo;
    }
  }

  for (int k0 = 0; k0 < 768; k0 += 32) {
    __syncthreads();
    // async B stage (4 x 4KB)
    gl16(gBh + k0, lBh_w);
    gl16(gBh + k0 + 64 * 768, lBh_w + 64 * 32);
    gl16(gBl + k0, lBl_w);
    gl16(gBl + k0 + 64 * 768, lBl_w + 64 * 32);
    // A ds_write from regs
#pragma unroll
    for (int it = 0; it < 2; ++it) {
      const int off = (it * 64 + ar_) * 40 + ac_ * 8;
      *(bf16x8*)(lAh + off) = pAh[it];
      *(bf16x8*)(lAl + off) = pAl[it];
    }
    // prefetch+split A for next k-step (overlaps MFMA phase)
    if (k0 + 32 < 768) {
#pragma unroll
      for (int it = 0; it < 2; ++it) {
        const float* p = Abase + (size_t)(it * 64 + ar_) * 768 + (k0 + 32) + ac_ * 8;
        float4 f0 = *(const float4*)p;
        float4 f1 = *(const float4*)(p + 4);
        float fa[8] = {f0.x, f0.y, f0.z, f0.w, f1.x, f1.y, f1.z, f1.w};
#pragma unroll
        for (int j = 0; j < 8; ++j) {
          unsigned short hi, lo;
          split2(fa[j], hi, lo);
          pAh[it][j] = (short)hi; pAl[it][j] = (short)lo;
        }
      }
    }
    __syncthreads();

    bf16x8 ah[4], al[4], bhf[4], blf[4];
#pragma unroll
    for (int mf = 0; mf < 4; ++mf) {
      const int off = (wr * 64 + mf * 16 + arow) * 40 + agrp * 8;
      ah[mf] = *(const bf16x8*)(lAh + off);
      al[mf] = *(const bf16x8*)(lAl + off);
    }
#pragma unroll
    for (int nf = 0; nf < 4; ++nf) {
      const int off = (wc * 64 + nf * 16 + arow) * 32 + agrp * 8;
      bhf[nf] = *(const bf16x8*)(lBh + off);
      blf[nf] = *(const bf16x8*)(lBl + off);
    }
#pragma unroll
    for (int mf = 0; mf < 4; ++mf)
#pragma unroll
      for (int nf = 0; nf < 4; ++nf) {
        acc[mf][nf] = __builtin_amdgcn_mfma_f32_16x16x32_bf16(ah[mf], bhf[nf], acc[mf][nf], 0, 0, 0);
        acc[mf][nf] = __builtin_amdgcn_mfma_f32_16x16x32_bf16(ah[mf], blf[nf], acc[mf][nf], 0, 0, 0);
        acc[mf][nf] = __builtin_amdgcn_mfma_f32_16x16x32_bf16(al[mf], bhf[nf], acc[mf][nf], 0, 0, 0);
      }
  }

  // epilogue: scatter split q/k (row-major) and v (transposed)
#pragma unroll
  for (int nf = 0; nf < 4; ++nf) {
    const int cg = c0 + wc * 64 + nf * 16 + arow;
    const int t = cg / 768;
    const int rem = cg - t * 768;
    const int h = rem >> 6;
    const int d = rem & 63;
    unsigned short* hi_arr = ws_split + (size_t)(half * 6 + t * 2) * SZC;
    unsigned short* lo_arr = hi_arr + SZC;
    const size_t bh_ = (size_t)(b * HEADS + h);
#pragma unroll
    for (int mf = 0; mf < 4; ++mf) {
#pragma unroll
      for (int ri = 0; ri < 4; ++ri) {
        const int n = nloc + wr * 64 + mf * 16 + agrp * 4 + ri;
        unsigned short hi, lo;
        split2(acc[mf][nf][ri], hi, lo);
        size_t idx;
        if (t < 2) idx = (bh_ * NSEQ + n) * HD + d;
        else       idx = (bh_ * HD + d) * NSEQ + n;
        hi_arr[idx] = hi;
        lo_arr[idx] = lo;
      }
    }
  }
}

// ---------------------------------------------------------------------------
// Proj GEMM: both sides pre-split bf16 via global_load_lds (linear LDS).
// EPI 1: fp32 d_out[:, N:] + bias.  EPI 2: vt2 transposed split + bias.
// ---------------------------------------------------------------------------
template <int EPI>
__global__ __launch_bounds__(256) void proj_gemm_k(
    const unsigned short* __restrict__ Ah, const unsigned short* __restrict__ Al,
    const unsigned short* __restrict__ Bh, const unsigned short* __restrict__ Bl,
    const float* __restrict__ bias,
    float* __restrict__ outf,
    unsigned short* __restrict__ vt_hi, unsigned short* __restrict__ vt_lo)
{
  __shared__ __attribute__((aligned(16))) unsigned short lds[16384];  // 32 KB
  unsigned short* const lAh = lds;           // [128][32] each, linear
  unsigned short* const lAl = lds + 4096;
  unsigned short* const lBh = lds + 8192;
  unsigned short* const lBl = lds + 12288;

  const int tid = threadIdx.x;
  const int lane = tid & 63;
  const int wave = tid >> 6;
  const int wr = wave >> 1, wc = wave & 1;
  const int arow = lane & 15, agrp = lane >> 4;

  // swizzle: nwg = 6*32 = 192, /8 = 24
  int flat = blockIdx.x + 6 * blockIdx.y;
  flat = (flat & 7) * 24 + (flat >> 3);
  const int bx = flat % 6;
  const int by = flat / 6;
  const int m0 = by * 128;
  const int c0 = bx * 128;

  const unsigned short* gAh = Ah + (size_t)(m0 + (tid >> 2)) * 768 + (tid & 3) * 8;
  const unsigned short* gAl = Al + (size_t)(m0 + (tid >> 2)) * 768 + (tid & 3) * 8;
  const unsigned short* gBh = Bh + (size_t)(c0 + (tid >> 2)) * 768 + (tid & 3) * 8;
  const unsigned short* gBl = Bl + (size_t)(c0 + (tid >> 2)) * 768 + (tid & 3) * 8;
  const int wb = (wave * 16) * 32;

  f32x4 acc[4][4];
#pragma unroll
  for (int i = 0; i < 4; ++i)
#pragma unroll
    for (int j = 0; j < 4; ++j) acc[i][j] = f32x4{0.f, 0.f, 0.f, 0.f};

  for (int k0 = 0; k0 < 768; k0 += 32) {
    __syncthreads();
    gl16(gAh + k0, lAh + wb);
    gl16(gAh + k0 + 64 * 768, lAh + wb + 64 * 32);
    gl16(gAl + k0, lAl + wb);
    gl16(gAl + k0 + 64 * 768, lAl + wb + 64 * 32);
    gl16(gBh + k0, lBh + wb);
    gl16(gBh + k0 + 64 * 768, lBh + wb + 64 * 32);
    gl16(gBl + k0, lBl + wb);
    gl16(gBl + k0 + 64 * 768, lBl + wb + 64 * 32);
    __syncthreads();

    bf16x8 ah[4], al[4], bhf[4], blf[4];
#pragma unroll
    for (int mf = 0; mf < 4; ++mf) {
      const int off = (wr * 64 + mf * 16 + arow) * 32 + agrp * 8;
      ah[mf] = *(const bf16x8*)(lAh + off);
      al[mf] = *(const bf16x8*)(lAl + off);
    }
#pragma unroll
    for (int nf = 0; nf < 4; ++nf) {
      const int off = (wc * 64 + nf * 16 + arow) * 32 + agrp * 8;
      bhf[nf] = *(const bf16x8*)(lBh + off);
      blf[nf] = *(const bf16x8*)(lBl + off);
    }
#pragma unroll
    for (int mf = 0; mf < 4; ++mf)
#pragma unroll
      for (int nf = 0; nf < 4; ++nf) {
        acc[mf][nf] = __builtin_amdgcn_mfma_f32_16x16x32_bf16(ah[mf], bhf[nf], acc[mf][nf], 0, 0, 0);
        acc[mf][nf] = __builtin_amdgcn_mfma_f32_16x16x32_bf16(ah[mf], blf[nf], acc[mf][nf], 0, 0, 0);
        acc[mf][nf] = __builtin_amdgcn_mfma_f32_16x16x32_bf16(al[mf], bhf[nf], acc[mf][nf], 0, 0, 0);
      }
  }

  if constexpr (EPI == 1) {
#pragma unroll
    for (int nf = 0; nf < 4; ++nf) {
      const int cg = c0 + wc * 64 + nf * 16 + arow;
      const float bv = bias[cg];
#pragma unroll
      for (int mf = 0; mf < 4; ++mf) {
#pragma unroll
        for (int ri = 0; ri < 4; ++ri) {
          const int m = m0 + wr * 64 + mf * 16 + agrp * 4 + ri;
          const int bb = m >> 10, n = m & 1023;
          outf[(size_t)bb * (2048 * 768) + (size_t)(1024 + n) * 768 + cg] =
              acc[mf][nf][ri] + bv;
        }
      }
    }
  } else {  // EPI == 2: transposed split (B,H,64,N)
#pragma unroll
    for (int nf = 0; nf < 4; ++nf) {
      const int cg = c0 + wc * 64 + nf * 16 + arow;
      const int h = cg >> 6, d = cg & 63;
      const float bv = bias[cg];
#pragma unroll
      for (int mf = 0; mf < 4; ++mf) {
#pragma unroll
        for (int ri = 0; ri < 4; ++ri) {
          const int m = m0 + wr * 64 + mf * 16 + agrp * 4 + ri;
          const int bb = m >> 10, n = m & 1023;
          unsigned short hi, lo;
          split2(acc[mf][nf][ri] + bv, hi, lo);
          const size_t idx = ((size_t)(bb * HEADS + h) * HD + d) * NSEQ + n;
          vt_hi[idx] = hi;
          vt_lo[idx] = lo;
        }
      }
    }
  }
}

// ---------------------------------------------------------------------------
// Attention core macros shared by single/fused kernels (split-bf16 flash).
// K/V staged by global_load_lds with pre-swizzled global source (linear LDS
// dest); ds_reads use chunk^(row&7) 16B swizzle. P packed via per-wave LDS.
// ---------------------------------------------------------------------------
__global__ __launch_bounds__(256) void attn_single_k(
    const unsigned short* __restrict__ q_hi, const unsigned short* __restrict__ q_lo,
    const unsigned short* __restrict__ k_hi, const unsigned short* __restrict__ k_lo,
    const unsigned short* __restrict__ vt_hi, const unsigned short* __restrict__ vt_lo,
    unsigned short* __restrict__ osph, unsigned short* __restrict__ ospl)
{
  __shared__ __attribute__((aligned(16))) unsigned char lds[50176];
  unsigned char* const ldsK_hi = lds;
  unsigned char* const ldsK_lo = lds + 8192;
  unsigned char* const ldsV_hi = lds + 16384;
  unsigned char* const ldsV_lo = lds + 24576;

  const int tid  = threadIdx.x;
  const int wave = tid >> 6;
  const int lane = tid & 63;

  // swizzle: nwg = 16*12*4 = 768, /8 = 96
  int flat = blockIdx.x + 16 * blockIdx.y + 192 * blockIdx.z;
  flat = (flat & 7) * 96 + (flat >> 3);
  const int bxq = flat & 15;
  const int h = (flat >> 4) % 12;
  const int b = flat / 192;
  const int bh = b * HEADS + h;
  const int q0 = bxq * 64 + wave * 16;

  unsigned int* const ldsP = (unsigned int*)(lds + 32768) + wave * (16 * 68);

  const int arow = lane & 15;
  const int agrp = lane >> 4;

  bf16x8 qh[2], ql[2];
  {
    const unsigned short* qp = q_hi + ((size_t)bh * NSEQ + q0 + arow) * HD + agrp * 8;
    qh[0] = *(const bf16x8*)qp;
    qh[1] = *(const bf16x8*)(qp + 32);
    const unsigned short* qp2 = q_lo + ((size_t)bh * NSEQ + q0 + arow) * HD + agrp * 8;
    ql[0] = *(const bf16x8*)qp2;
    ql[1] = *(const bf16x8*)(qp2 + 32);
  }

  f32x4 acc[4];
#pragma unroll
  for (int i = 0; i < 4; ++i) acc[i] = f32x4{0.f, 0.f, 0.f, 0.f};
  float m_run[4], l_run[4];
#pragma unroll
  for (int r = 0; r < 4; ++r) { m_run[r] = -3.0e38f; l_run[r] = 0.f; }

  // staging lanes: r = tid>>3 (32 rows/call), c = tid&7; source pre-swizzled
  const int sr = tid >> 3, sc = tid & 7;
  const int swzc = ((sc ^ (sr & 7)) << 3);  // ushort offset within row
  const size_t kbase = (size_t)bh * NSEQ * HD;
  const size_t vbase = (size_t)bh * HD * NSEQ;
  const unsigned short* gKh = k_hi + kbase + (size_t)sr * 64 + swzc;
  const unsigned short* gKl = k_lo + kbase + (size_t)sr * 64 + swzc;
  const unsigned short* gVh = vt_hi + vbase + (size_t)sr * NSEQ + swzc;
  const unsigned short* gVl = vt_lo + vbase + (size_t)sr * NSEQ + swzc;
  const int ldsw = (wave * 8) * 128;  // wave-uniform byte base (8 rows/wave/call)

  for (int j0 = 0; j0 < NSEQ; j0 += 64) {
    __syncthreads();
    gl16(gKh + j0 * 64, ldsK_hi + ldsw);
    gl16(gKh + j0 * 64 + 2048, ldsK_hi + ldsw + 4096);
    gl16(gKl + j0 * 64, ldsK_lo + ldsw);
    gl16(gKl + j0 * 64 + 2048, ldsK_lo + ldsw + 4096);
    gl16(gVh + j0, ldsV_hi + ldsw);
    gl16(gVh + j0 + 32 * NSEQ, ldsV_hi + ldsw + 4096);
    gl16(gVl + j0, ldsV_lo + ldsw);
    gl16(gVl + j0 + 32 * NSEQ, ldsV_lo + ldsw + 4096);
    __syncthreads();

    f32x4 s[4];
#pragma unroll
    for (int nt = 0; nt < 4; ++nt) s[nt] = f32x4{0.f, 0.f, 0.f, 0.f};
#pragma unroll
    for (int ks = 0; ks < 2; ++ks) {
#pragma unroll
      for (int nt = 0; nt < 4; ++nt) {
        const int krow = nt * 16 + arow;
        const int chunk = ks * 4 + agrp;
        const int off = krow * 128 + (((chunk ^ (krow & 7)) << 4));
        bf16x8 bh_ = *(const bf16x8*)(ldsK_hi + off);
        bf16x8 bl_ = *(const bf16x8*)(ldsK_lo + off);
        s[nt] = __builtin_amdgcn_mfma_f32_16x16x32_bf16(qh[ks], bh_, s[nt], 0, 0, 0);
        s[nt] = __builtin_amdgcn_mfma_f32_16x16x32_bf16(qh[ks], bl_, s[nt], 0, 0, 0);
        s[nt] = __builtin_amdgcn_mfma_f32_16x16x32_bf16(ql[ks], bh_, s[nt], 0, 0, 0);
      }
    }
#pragma unroll
    for (int nt = 0; nt < 4; ++nt) s[nt] *= 0.125f;

    float corr[4], rsum[4];
#pragma unroll
    for (int r = 0; r < 4; ++r) {
      float mx = fmaxf(fmaxf(s[0][r], s[1][r]), fmaxf(s[2][r], s[3][r]));
      mx = fmaxf(mx, __shfl_xor(mx, 1, 64));
      mx = fmaxf(mx, __shfl_xor(mx, 2, 64));
      mx = fmaxf(mx, __shfl_xor(mx, 4, 64));
      mx = fmaxf(mx, __shfl_xor(mx, 8, 64));
      float mnew = fmaxf(m_run[r], mx);
      corr[r] = __expf(m_run[r] - mnew);
      m_run[r] = mnew;
      rsum[r] = 0.f;
    }
#pragma unroll
    for (int nt = 0; nt < 4; ++nt) {
#pragma unroll
      for (int r = 0; r < 4; ++r) {
        float p = __expf(s[nt][r] - m_run[r]);
        rsum[r] += p;
        unsigned short ph, pl;
        split2(p, ph, pl);
        ldsP[(agrp * 4 + r) * 68 + nt * 16 + arow] =
            (unsigned int)ph | ((unsigned int)pl << 16);
      }
    }
#pragma unroll
    for (int r = 0; r < 4; ++r) {
      float sm = rsum[r];
      sm += __shfl_xor(sm, 1, 64);
      sm += __shfl_xor(sm, 2, 64);
      sm += __shfl_xor(sm, 4, 64);
      sm += __shfl_xor(sm, 8, 64);
      l_run[r] = l_run[r] * corr[r] + sm;
#pragma unroll
      for (int nt2 = 0; nt2 < 4; ++nt2) acc[nt2][r] *= corr[r];
    }

#pragma unroll
    for (int kk = 0; kk < 2; ++kk) {
      const unsigned int* prow = ldsP + arow * 68 + kk * 32 + agrp * 8;
      u32x4v w0 = *(const u32x4v*)prow;
      u32x4v w1 = *(const u32x4v*)(prow + 4);
      bf16x8 pa_h, pa_l;
#pragma unroll
      for (int i = 0; i < 4; ++i) {
        pa_h[i]     = (short)(w0[i] & 0xffffu);
        pa_l[i]     = (short)(w0[i] >> 16);
        pa_h[4 + i] = (short)(w1[i] & 0xffffu);
        pa_l[4 + i] = (short)(w1[i] >> 16);
      }
#pragma unroll
      for (int nt2 = 0; nt2 < 4; ++nt2) {
        const int vrow = nt2 * 16 + arow;
        const int chunk = kk * 4 + agrp;
        const int off = vrow * 128 + (((chunk ^ (vrow & 7)) << 4));
        bf16x8 vh_ = *(const bf16x8*)(ldsV_hi + off);
        bf16x8 vl_ = *(const bf16x8*)(ldsV_lo + off);
        acc[nt2] = __builtin_amdgcn_mfma_f32_16x16x32_bf16(pa_h, vh_, acc[nt2], 0, 0, 0);
        acc[nt2] = __builtin_amdgcn_mfma_f32_16x16x32_bf16(pa_h, vl_, acc[nt2], 0, 0, 0);
        acc[nt2] = __builtin_amdgcn_mfma_f32_16x16x32_bf16(pa_l, vh_, acc[nt2], 0, 0, 0);
      }
    }
  }

  // epilogue: split osp (B*N, 768)
#pragma unroll
  for (int r = 0; r < 4; ++r) {
    const float inv = 1.f / l_run[r];
    const int n = q0 + agrp * 4 + r;
    const size_t obase = ((size_t)(b * NSEQ + n)) * C_DIM + h * HD + arow;
#pragma unroll
    for (int nt2 = 0; nt2 < 4; ++nt2) {
      unsigned short hi, lo;
      split2(acc[nt2][r] * inv, hi, lo);
      osph[obase + nt2 * 16] = hi;
      ospl[obase + nt2 * 16] = lo;
    }
  }
}

// ---------------------------------------------------------------------------
// Fused attention (steps 4+5): shared QK^T + softmax, two PV passes.
// VA -> fp32 out1 (d_out[:, :N]); VB -> split osp.
// ---------------------------------------------------------------------------
__global__ __launch_bounds__(256) void attn_fused_k(
    const unsigned short* __restrict__ q_hi, const unsigned short* __restrict__ q_lo,
    const unsigned short* __restrict__ k_hi, const unsigned short* __restrict__ k_lo,
    const unsigned short* __restrict__ vAh_, const unsigned short* __restrict__ vAl_,
    const unsigned short* __restrict__ vBh_, const unsigned short* __restrict__ vBl_,
    float* __restrict__ out1,
    unsigned short* __restrict__ osph, unsigned short* __restrict__ ospl)
{
  __shared__ __attribute__((aligned(16))) unsigned char lds[66560];
  unsigned char* const ldsK_hi = lds;
  unsigned char* const ldsK_lo = lds + 8192;
  unsigned char* const ldsA_hi = lds + 16384;
  unsigned char* const ldsA_lo = lds + 24576;
  unsigned char* const ldsB_hi = lds + 32768;
  unsigned char* const ldsB_lo = lds + 40960;

  const int tid  = threadIdx.x;
  const int wave = tid >> 6;
  const int lane = tid & 63;

  int flat = blockIdx.x + 16 * blockIdx.y + 192 * blockIdx.z;
  flat = (flat & 7) * 96 + (flat >> 3);
  const int bxq = flat & 15;
  const int h = (flat >> 4) % 12;
  const int b = flat / 192;
  const int bh = b * HEADS + h;
  const int q0 = bxq * 64 + wave * 16;

  unsigned int* const ldsP = (unsigned int*)(lds + 49152) + wave * (16 * 68);

  const int arow = lane & 15;
  const int agrp = lane >> 4;

  bf16x8 qh[2], ql[2];
  {
    const unsigned short* qp = q_hi + ((size_t)bh * NSEQ + q0 + arow) * HD + agrp * 8;
    qh[0] = *(const bf16x8*)qp;
    qh[1] = *(const bf16x8*)(qp + 32);
    const unsigned short* qp2 = q_lo + ((size_t)bh * NSEQ + q0 + arow) * HD + agrp * 8;
    ql[0] = *(const bf16x8*)qp2;
    ql[1] = *(const bf16x8*)(qp2 + 32);
  }

  f32x4 acc1[4], acc2[4];
#pragma unroll
  for (int i = 0; i < 4; ++i) {
    acc1[i] = f32x4{0.f, 0.f, 0.f, 0.f};
    acc2[i] = f32x4{0.f, 0.f, 0.f, 0.f};
  }
  float m_run[4], l_run[4];
#pragma unroll
  for (int r = 0; r < 4; ++r) { m_run[r] = -3.0e38f; l_run[r] = 0.f; }

  const int sr = tid >> 3, sc = tid & 7;
  const int swzc = ((sc ^ (sr & 7)) << 3);
  const size_t kbase = (size_t)bh * NSEQ * HD;
  const size_t vbase = (size_t)bh * HD * NSEQ;
  const unsigned short* gKh = k_hi + kbase + (size_t)sr * 64 + swzc;
  const unsigned short* gKl = k_lo + kbase + (size_t)sr * 64 + swzc;
  const unsigned short* gAh = vAh_ + vbase + (size_t)sr * NSEQ + swzc;
  const unsigned short* gAl = vAl_ + vbase + (size_t)sr * NSEQ + swzc;
  const unsigned short* gBh = vBh_ + vbase + (size_t)sr * NSEQ + swzc;
  const unsigned short* gBl = vBl_ + vbase + (size_t)sr * NSEQ + swzc;
  const int ldsw = (wave * 8) * 128;

  for (int j0 = 0; j0 < NSEQ; j0 += 64) {
    __syncthreads();
    gl16(gKh + j0 * 64, ldsK_hi + ldsw);
    gl16(gKh + j0 * 64 + 2048, ldsK_hi + ldsw + 4096);
    gl16(gKl + j0 * 64, ldsK_lo + ldsw);
    gl16(gKl + j0 * 64 + 2048, ldsK_lo + ldsw + 4096);
    gl16(gAh + j0, ldsA_hi + ldsw);
    gl16(gAh + j0 + 32 * NSEQ, ldsA_hi + ldsw + 4096);
    gl16(gAl + j0, ldsA_lo + ldsw);
    gl16(gAl + j0 + 32 * NSEQ, ldsA_lo + ldsw + 4096);
    gl16(gBh + j0, ldsB_hi + ldsw);
    gl16(gBh + j0 + 32 * NSEQ, ldsB_hi + ldsw + 4096);
    gl16(gBl + j0, ldsB_lo + ldsw);
    gl16(gBl + j0 + 32 * NSEQ, ldsB_lo + ldsw + 4096);
    __syncthreads();

    f32x4 s[4];
#pragma unroll
    for (int nt = 0; nt < 4; ++nt) s[nt] = f32x4{0.f, 0.f, 0.f, 0.f};
#pragma unroll
    for (int ks = 0; ks < 2; ++ks) {
#pragma unroll
      for (int nt = 0; nt < 4; ++nt) {
        const int krow = nt * 16 + arow;
        const int chunk = ks * 4 + agrp;
        const int off = krow * 128 + (((chunk ^ (krow & 7)) << 4));
        bf16x8 bh_ = *(const bf16x8*)(ldsK_hi + off);
        bf16x8 bl_ = *(const bf16x8*)(ldsK_lo + off);
        s[nt] = __builtin_amdgcn_mfma_f32_16x16x32_bf16(qh[ks], bh_, s[nt], 0, 0, 0);
        s[nt] = __builtin_amdgcn_mfma_f32_16x16x32_bf16(qh[ks], bl_, s[nt], 0, 0, 0);
        s[nt] = __builtin_amdgcn_mfma_f32_16x16x32_bf16(ql[ks], bh_, s[nt], 0, 0, 0);
      }
    }
#pragma unroll
    for (int nt = 0; nt < 4; ++nt) s[nt] *= 0.125f;

    float corr[4], rsum[4];
#pragma unroll
    for (int r = 0; r < 4; ++r) {
      float mx = fmaxf(fmaxf(s[0][r], s[1][r]), fmaxf(s[2][r], s[3][r]));
      mx = fmaxf(mx, __shfl_xor(mx, 1, 64));
      mx = fmaxf(mx, __shfl_xor(mx, 2, 64));
      mx = fmaxf(mx, __shfl_xor(mx, 4, 64));
      mx = fmaxf(mx, __shfl_xor(mx, 8, 64));
      float mnew = fmaxf(m_run[r], mx);
      corr[r] = __expf(m_run[r] - mnew);
      m_run[r] = mnew;
      rsum[r] = 0.f;
    }
#pragma unroll
    for (int nt = 0; nt < 4; ++nt) {
#pragma unroll
      for (int r = 0; r < 4; ++r) {
        float p = __expf(s[nt][r] - m_run[r]);
        rsum[r] += p;
        unsigned short ph, pl;
        split2(p, ph, pl);
        ldsP[(agrp * 4 + r) * 68 + nt * 16 + arow] =
            (unsigned int)ph | ((unsigned int)pl << 16);
      }
    }
#pragma unroll
    for (int r = 0; r < 4; ++r) {
      float sm = rsum[r];
      sm += __shfl_xor(sm, 1, 64);
      sm += __shfl_xor(sm, 2, 64);
      sm += __shfl_xor(sm, 4, 64);
      sm += __shfl_xor(sm, 8, 64);
      l_run[r] = l_run[r] * corr[r] + sm;
#pragma unroll
      for (int nt2 = 0; nt2 < 4; ++nt2) {
        acc1[nt2][r] *= corr[r];
        acc2[nt2][r] *= corr[r];
      }
    }

#pragma unroll
    for (int kk = 0; kk < 2; ++kk) {
      const unsigned int* prow = ldsP + arow * 68 + kk * 32 + agrp * 8;
      u32x4v w0 = *(const u32x4v*)prow;
      u32x4v w1 = *(const u32x4v*)(prow + 4);
      bf16x8 pa_h, pa_l;
#pragma unroll
      for (int i = 0; i < 4; ++i) {
        pa_h[i]     = (short)(w0[i] & 0xffffu);
        pa_l[i]     = (short)(w0[i] >> 16);
        pa_h[4 + i] = (short)(w1[i] & 0xffffu);
        pa_l[4 + i] = (short)(w1[i] >> 16);
      }
#pragma unroll
      for (int nt2 = 0; nt2 < 4; ++nt2) {
        const int vrow = nt2 * 16 + arow;
        const int chunk = kk * 4 + agrp;
        const int off = vrow * 128 + (((chunk ^ (vrow & 7)) << 4));
        bf16x8 vh_ = *(const bf16x8*)(ldsA_hi + off);
        bf16x8 vl_ = *(const bf16x8*)(ldsA_lo + off);
        acc1[nt2] = __builtin_amdgcn_mfma_f32_16x16x32_bf16(pa_h, vh_, acc1[nt2], 0, 0, 0);
        acc1[nt2] = __builtin_amdgcn_mfma_f32_16x16x32_bf16(pa_h, vl_, acc1[nt2], 0, 0, 0);
        acc1[nt2] = __builtin_amdgcn_mfma_f32_16x16x32_bf16(pa_l, vh_, acc1[nt2], 0, 0, 0);
        bf16x8 uh_ = *(const bf16x8*)(ldsB_hi + off);
        bf16x8 ul_ = *(const bf16x8*)(ldsB_lo + off);
        acc2[nt2] = __builtin_amdgcn_mfma_f32_16x16x32_bf16(pa_h, uh_, acc2[nt2], 0, 0, 0);
        acc2[nt2] = __builtin_amdgcn_mfma_f32_16x16x32_bf16(pa_h, ul_, acc2[nt2], 0, 0, 0);
        acc2[nt2] = __builtin_amdgcn_mfma_f32_16x16x32_bf16(pa_l, uh_, acc2[nt2], 0, 0, 0);
      }
    }
  }

#pragma unroll
  for (int r = 0; r < 4; ++r) {
    const float inv = 1.f / l_run[r];
    const int n = q0 + agrp * 4 + r;
    float* rowp = out1 + (size_t)b * (2048 * C_DIM) + (size_t)n * C_DIM + h * HD + arow;
    const size_t obase = ((size_t)(b * NSEQ + n)) * C_DIM + h * HD + arow;
#pragma unroll
    for (int nt2 = 0; nt2 < 4; ++nt2) {
      rowp[nt2 * 16] = acc1[nt2][r] * inv;
      unsigned short hi, lo;
      split2(acc2[nt2][r] * inv, hi, lo);
      osph[obase + nt2 * 16] = hi;
      ospl[obase + nt2 * 16] = lo;
    }
  }
}

// ---------------------------------------------------------------------------
extern "C" void kernel_launch(void* const* d_in, const int* in_sizes, int n_in,
                              void* d_out, int out_size, void* d_ws, size_t ws_size,
                              hipStream_t stream)
{
  const float* x           = (const float*)d_in[0];
  const float* w_qkv_diff  = (const float*)d_in[1];
  const float* w_qkv_cond  = (const float*)d_in[2];
  const float* w_proj_diff = (const float*)d_in[3];
  const float* b_proj_diff = (const float*)d_in[4];
  const float* w_proj_cond = (const float*)d_in[5];
  const float* b_proj_cond = (const float*)d_in[6];
  float* out = (float*)d_out;

  const size_t SZ = SZC;
  const size_t WQ = 2304 * 768;
  const size_t WP = 768 * 768;
  unsigned short* sw = (unsigned short*)d_ws;
  unsigned short* qd_hi  = sw + 0 * SZ;
  unsigned short* qd_lo  = sw + 1 * SZ;
  unsigned short* kd_hi  = sw + 2 * SZ;
  unsigned short* kd_lo  = sw + 3 * SZ;
  unsigned short* vtd_hi = sw + 4 * SZ;
  unsigned short* vtd_lo = sw + 5 * SZ;
  unsigned short* qc_hi  = sw + 6 * SZ;
  unsigned short* qc_lo  = sw + 7 * SZ;
  unsigned short* kc_hi  = sw + 8 * SZ;
  unsigned short* kc_lo  = sw + 9 * SZ;
  unsigned short* vtc_hi = sw + 10 * SZ;
  unsigned short* vtc_lo = sw + 11 * SZ;
  unsigned short* wqdT_h = sw + 12 * SZ;
  unsigned short* wqdT_l = wqdT_h + WQ;
  unsigned short* wqcT_h = wqdT_l + WQ;
  unsigned short* wqcT_l = wqcT_h + WQ;
  unsigned short* wpdT_h = wqcT_l + WQ;
  unsigned short* wpdT_l = wpdT_h + WP;
  unsigned short* wpcT_h = wpdT_l + WP;
  unsigned short* wpcT_l = wpcT_h + WP;
  // osp split (2*SZ = 6.29M us) aliases wq*T (4*WQ = 7.08M us, dead after qkv)
  unsigned short* osph = wqdT_h;
  unsigned short* ospl = wqdT_h + SZ;
  // vt2 aliases q_d (dead after step 2)
  unsigned short* vt2_hi = qd_hi;
  unsigned short* vt2_lo = qd_lo;

  // 0. weight prep
  split_wT_k<<<dim3(72, 24), dim3(32, 8), 0, stream>>>(w_qkv_diff, 768, 2304, wqdT_h, wqdT_l);
  split_wT_k<<<dim3(72, 24), dim3(32, 8), 0, stream>>>(w_qkv_cond, 768, 2304, wqcT_h, wqcT_l);
  split_wT_k<<<dim3(24, 24), dim3(32, 8), 0, stream>>>(w_proj_diff, 768, 768, wpdT_h, wpdT_l);
  split_wT_k<<<dim3(24, 24), dim3(32, 8), 0, stream>>>(w_proj_cond, 768, 768, wpcT_h, wpcT_l);

  // 1. qkv both streams
  qkv_gemm_k<<<dim3(18, 32, 2), 256, 0, stream>>>(
      x, wqdT_h, wqdT_l, wqcT_h, wqcT_l, sw);

  // 2. attn_diff -> osp split
  attn_single_k<<<dim3(16, 12, 4), 256, 0, stream>>>(
      qd_hi, qd_lo, kd_hi, kd_lo, vtd_hi, vtd_lo, osph, ospl);

  // 3. (osp @ w_proj_diff + b)^T split -> vt2
  proj_gemm_k<2><<<dim3(6, 32), 256, 0, stream>>>(
      osph, ospl, wpdT_h, wpdT_l, b_proj_diff, nullptr, vt2_hi, vt2_lo);

  // 4+5. fused attn_cond: P @ vt2 -> out[:, :N] fp32 ; P @ vt_c -> osp split
  attn_fused_k<<<dim3(16, 12, 4), 256, 0, stream>>>(
      qc_hi, qc_lo, kc_hi, kc_lo, vt2_hi, vt2_lo, vtc_hi, vtc_lo, out, osph, ospl);

  // 6. out[:, N:] = osp @ w_proj_cond + b
  proj_gemm_k<1><<<dim3(6, 32), 256, 0, stream>>>(
      osph, ospl, wpcT_h, wpcT_l, b_proj_cond, out, nullptr, nullptr);
}

// Round 5
// 388.958 us; speedup vs baseline: 8.1785x; 1.0132x over previous
//
#include <hip/hip_runtime.h>
#include <hip/hip_bf16.h>

// B=4, N0=2048 (N=1024 diff + 1024 cond), C=768, H=12, hd=64. All fp32 I/O.
// Split-bf16 (x = hi + lo, 3 bf16-MFMA terms) for all GEMM/attention math.
//   0. weight prep: wT[n][k] split hi/lo for all 4 weight matrices
//   1. qkv both streams  [MFMA] -> split q/k (B,H,N,64) + vt (B,H,64,N) hi/lo
//   2. osp = attn(q_d,k_d,vt_d)              [MFMA] -> SPLIT (B*N,768) hi/lo
//   3. vt2 = (osp @ w_proj_diff + b)^T split [MFMA] -> (B,H,64,N) hi/lo
//   4+5 fused: P = softmax(q_c k_c^T) once;
//        out[:, :N] = P @ vt2 (fp32), osp = P @ vt_c (split)
//   6. out[:, N:] = osp @ w_proj_cond + b    [MFMA]
//
// GEMM LDS tiles [128][32]us (64B rows): bank-conflict fix = chunk^((row>>1)&3)
// involution (write-source and read side) -> 2-way max (free).

#define C_DIM 768
#define HEADS 12
#define HD 64
#define NSEQ 1024
#define BATCH 4
#define SZC 3145728  // BATCH*HEADS*NSEQ*HD

typedef short bf16x8 __attribute__((ext_vector_type(8)));
typedef float f32x4 __attribute__((ext_vector_type(4)));
typedef unsigned int u32x4v __attribute__((ext_vector_type(4)));

typedef __attribute__((address_space(3))) unsigned int lds_u32_t;
typedef __attribute__((address_space(1))) const unsigned int glb_u32_t;

__device__ __forceinline__ void gl16(const void* g, void* l) {
  __builtin_amdgcn_global_load_lds((glb_u32_t*)g, (lds_u32_t*)l, 16, 0, 0);
}

__device__ __forceinline__ unsigned short f2bf(float x) {
  __hip_bfloat16 h = __float2bfloat16(x);
  return *reinterpret_cast<unsigned short*>(&h);
}
__device__ __forceinline__ float bf2f(unsigned short u) {
  __hip_bfloat16 h = *reinterpret_cast<__hip_bfloat16*>(&u);
  return __bfloat162float(h);
}
__device__ __forceinline__ void split2(float x, unsigned short& hi, unsigned short& lo) {
  unsigned short h = f2bf(x);
  lo = f2bf(x - bf2f(h));
  hi = h;
}

// ---------------------------------------------------------------------------
// Weight prep: w (K x N fp32, row-major) -> wT hi/lo (N x K bf16 split).
// ---------------------------------------------------------------------------
__global__ __launch_bounds__(256) void split_wT_k(
    const float* __restrict__ w, int K, int N,
    unsigned short* __restrict__ th, unsigned short* __restrict__ tl)
{
  __shared__ float T[32][33];
  const int n0 = blockIdx.x * 32, k0 = blockIdx.y * 32;
  const int tx = threadIdx.x, ty = threadIdx.y;
#pragma unroll
  for (int i = 0; i < 4; ++i) {
    int k = ty + i * 8;
    T[k][tx] = w[(size_t)(k0 + k) * N + n0 + tx];
  }
  __syncthreads();
#pragma unroll
  for (int i = 0; i < 4; ++i) {
    int n = ty + i * 8;
    float v = T[tx][n];
    unsigned short hi, lo;
    split2(v, hi, lo);
    th[(size_t)(n0 + n) * K + k0 + tx] = hi;
    tl[(size_t)(n0 + n) * K + k0 + tx] = lo;
  }
}

// ---------------------------------------------------------------------------
// QKV GEMM: A = x fp32 (reg-split staging, prefetched, swizzled ds_write),
// B = pre-split weights via global_load_lds (pre-swizzled source). 128x128
// tile, BK=32, 4 waves. LDS 32 KB. Epilogue scatters split q/k + v^T.
// ---------------------------------------------------------------------------
__global__ __launch_bounds__(256) void qkv_gemm_k(
    const float* __restrict__ x,
    const unsigned short* __restrict__ wdh, const unsigned short* __restrict__ wdl,
    const unsigned short* __restrict__ wch, const unsigned short* __restrict__ wcl,
    unsigned short* __restrict__ ws_split)
{
  __shared__ __attribute__((aligned(16))) unsigned short lds[16384];  // 32 KB
  unsigned short* const lAh = lds;           // [128][32] swizzled
  unsigned short* const lAl = lds + 4096;
  unsigned short* const lBh = lds + 8192;
  unsigned short* const lBl = lds + 12288;

  const int tid = threadIdx.x;
  const int lane = tid & 63;
  const int wave = tid >> 6;
  const int wr = wave >> 1, wc = wave & 1;
  const int arow = lane & 15, agrp = lane >> 4;

  // XCD-aware bijective swizzle: nwg = 18*32*2 = 1152, 1152/8 = 144
  int flat = blockIdx.x + 18 * blockIdx.y + 576 * blockIdx.z;
  flat = (flat & 7) * 144 + (flat >> 3);
  const int bx = flat % 18;
  const int by = (flat / 18) & 31;
  const int half = flat / 576;

  const int m0 = by * 128;
  const int b = m0 >> 10, nloc = m0 & 1023;
  const int c0 = bx * 128;
  const unsigned short* __restrict__ BTh = half ? wch : wdh;
  const unsigned short* __restrict__ BTl = half ? wcl : wdl;
  const float* __restrict__ Abase = x + (size_t)(b * 2048 + half * 1024 + nloc) * 768;

  // B gload lanes: r = tid>>2 (row), c = tid&3 (16B chunk); source chunk
  // pre-swizzled by ^((r>>1)&3) so that swizzled ds_read recovers chunk j.
  const int gr = tid >> 2, gc = (tid & 3) ^ ((tid >> 3) & 3);
  const unsigned short* gBh = BTh + (size_t)(c0 + gr) * 768 + gc * 8;
  const unsigned short* gBl = BTl + (size_t)(c0 + gr) * 768 + gc * 8;
  unsigned short* const lBh_w = lBh + (wave * 16) * 32;  // wave-uniform dest
  unsigned short* const lBl_w = lBl + (wave * 16) * 32;

  const int ar_ = tid >> 2, ac_ = tid & 3;
  const int aswz = (ac_ ^ ((ar_ >> 1) & 3)) * 8;  // swizzled chunk pos for A write

  f32x4 acc[4][4];
#pragma unroll
  for (int i = 0; i < 4; ++i)
#pragma unroll
    for (int j = 0; j < 4; ++j) acc[i][j] = f32x4{0.f, 0.f, 0.f, 0.f};

  // prefetch+split A for k0 = 0
  bf16x8 pAh[2], pAl[2];
#pragma unroll
  for (int it = 0; it < 2; ++it) {
    const float* p = Abase + (size_t)(it * 64 + ar_) * 768 + ac_ * 8;
    float4 f0 = *(const float4*)p;
    float4 f1 = *(const float4*)(p + 4);
    float fa[8] = {f0.x, f0.y, f0.z, f0.w, f1.x, f1.y, f1.z, f1.w};
#pragma unroll
    for (int j = 0; j < 8; ++j) {
      unsigned short hi, lo;
      split2(fa[j], hi, lo);
      pAh[it][j] = (short)hi; pAl[it][j] = (short)lo;
    }
  }

  for (int k0 = 0; k0 < 768; k0 += 32) {
    __syncthreads();
    // async B stage (4 x 4KB), source pre-swizzled
    gl16(gBh + k0, lBh_w);
    gl16(gBh + k0 + 64 * 768, lBh_w + 64 * 32);
    gl16(gBl + k0, lBl_w);
    gl16(gBl + k0 + 64 * 768, lBl_w + 64 * 32);
    // A ds_write from regs at swizzled chunk position
#pragma unroll
    for (int it = 0; it < 2; ++it) {
      const int off = (it * 64 + ar_) * 32 + aswz;
      *(bf16x8*)(lAh + off) = pAh[it];
      *(bf16x8*)(lAl + off) = pAl[it];
    }
    // prefetch+split A for next k-step (overlaps MFMA phase)
    if (k0 + 32 < 768) {
#pragma unroll
      for (int it = 0; it < 2; ++it) {
        const float* p = Abase + (size_t)(it * 64 + ar_) * 768 + (k0 + 32) + ac_ * 8;
        float4 f0 = *(const float4*)p;
        float4 f1 = *(const float4*)(p + 4);
        float fa[8] = {f0.x, f0.y, f0.z, f0.w, f1.x, f1.y, f1.z, f1.w};
#pragma unroll
        for (int j = 0; j < 8; ++j) {
          unsigned short hi, lo;
          split2(fa[j], hi, lo);
          pAh[it][j] = (short)hi; pAl[it][j] = (short)lo;
        }
      }
    }
    __syncthreads();

    bf16x8 ah[4], al[4], bhf[4], blf[4];
#pragma unroll
    for (int mf = 0; mf < 4; ++mf) {
      const int row = wr * 64 + mf * 16 + arow;
      const int off = row * 32 + ((agrp ^ ((row >> 1) & 3)) << 3);
      ah[mf] = *(const bf16x8*)(lAh + off);
      al[mf] = *(const bf16x8*)(lAl + off);
    }
#pragma unroll
    for (int nf = 0; nf < 4; ++nf) {
      const int row = wc * 64 + nf * 16 + arow;
      const int off = row * 32 + ((agrp ^ ((row >> 1) & 3)) << 3);
      bhf[nf] = *(const bf16x8*)(lBh + off);
      blf[nf] = *(const bf16x8*)(lBl + off);
    }
#pragma unroll
    for (int mf = 0; mf < 4; ++mf)
#pragma unroll
      for (int nf = 0; nf < 4; ++nf) {
        acc[mf][nf] = __builtin_amdgcn_mfma_f32_16x16x32_bf16(ah[mf], bhf[nf], acc[mf][nf], 0, 0, 0);
        acc[mf][nf] = __builtin_amdgcn_mfma_f32_16x16x32_bf16(ah[mf], blf[nf], acc[mf][nf], 0, 0, 0);
        acc[mf][nf] = __builtin_amdgcn_mfma_f32_16x16x32_bf16(al[mf], bhf[nf], acc[mf][nf], 0, 0, 0);
      }
  }

  // epilogue: scatter split q/k (row-major) and v (transposed)
#pragma unroll
  for (int nf = 0; nf < 4; ++nf) {
    const int cg = c0 + wc * 64 + nf * 16 + arow;
    const int t = cg / 768;
    const int rem = cg - t * 768;
    const int h = rem >> 6;
    const int d = rem & 63;
    unsigned short* hi_arr = ws_split + (size_t)(half * 6 + t * 2) * SZC;
    unsigned short* lo_arr = hi_arr + SZC;
    const size_t bh_ = (size_t)(b * HEADS + h);
#pragma unroll
    for (int mf = 0; mf < 4; ++mf) {
#pragma unroll
      for (int ri = 0; ri < 4; ++ri) {
        const int n = nloc + wr * 64 + mf * 16 + agrp * 4 + ri;
        unsigned short hi, lo;
        split2(acc[mf][nf][ri], hi, lo);
        size_t idx;
        if (t < 2) idx = (bh_ * NSEQ + n) * HD + d;
        else       idx = (bh_ * HD + d) * NSEQ + n;
        hi_arr[idx] = hi;
        lo_arr[idx] = lo;
      }
    }
  }
}

// ---------------------------------------------------------------------------
// Proj GEMM: both sides pre-split bf16 via global_load_lds, pre-swizzled
// sources + swizzled reads (2-way max conflicts). LDS 32 KB.
// EPI 1: fp32 d_out[:, N:] + bias.  EPI 2: vt2 transposed split + bias.
// ---------------------------------------------------------------------------
template <int EPI>
__global__ __launch_bounds__(256) void proj_gemm_k(
    const unsigned short* __restrict__ Ah, const unsigned short* __restrict__ Al,
    const unsigned short* __restrict__ Bh, const unsigned short* __restrict__ Bl,
    const float* __restrict__ bias,
    float* __restrict__ outf,
    unsigned short* __restrict__ vt_hi, unsigned short* __restrict__ vt_lo)
{
  __shared__ __attribute__((aligned(16))) unsigned short lds[16384];  // 32 KB
  unsigned short* const lAh = lds;
  unsigned short* const lAl = lds + 4096;
  unsigned short* const lBh = lds + 8192;
  unsigned short* const lBl = lds + 12288;

  const int tid = threadIdx.x;
  const int lane = tid & 63;
  const int wave = tid >> 6;
  const int wr = wave >> 1, wc = wave & 1;
  const int arow = lane & 15, agrp = lane >> 4;

  // swizzle: nwg = 6*32 = 192, /8 = 24
  int flat = blockIdx.x + 6 * blockIdx.y;
  flat = (flat & 7) * 24 + (flat >> 3);
  const int bx = flat % 6;
  const int by = flat / 6;
  const int m0 = by * 128;
  const int c0 = bx * 128;

  const int gr = tid >> 2, gc = (tid & 3) ^ ((tid >> 3) & 3);
  const unsigned short* gAh = Ah + (size_t)(m0 + gr) * 768 + gc * 8;
  const unsigned short* gAl = Al + (size_t)(m0 + gr) * 768 + gc * 8;
  const unsigned short* gBh = Bh + (size_t)(c0 + gr) * 768 + gc * 8;
  const unsigned short* gBl = Bl + (size_t)(c0 + gr) * 768 + gc * 8;
  const int wb = (wave * 16) * 32;

  f32x4 acc[4][4];
#pragma unroll
  for (int i = 0; i < 4; ++i)
#pragma unroll
    for (int j = 0; j < 4; ++j) acc[i][j] = f32x4{0.f, 0.f, 0.f, 0.f};

  for (int k0 = 0; k0 < 768; k0 += 32) {
    __syncthreads();
    gl16(gAh + k0, lAh + wb);
    gl16(gAh + k0 + 64 * 768, lAh + wb + 64 * 32);
    gl16(gAl + k0, lAl + wb);
    gl16(gAl + k0 + 64 * 768, lAl + wb + 64 * 32);
    gl16(gBh + k0, lBh + wb);
    gl16(gBh + k0 + 64 * 768, lBh + wb + 64 * 32);
    gl16(gBl + k0, lBl + wb);
    gl16(gBl + k0 + 64 * 768, lBl + wb + 64 * 32);
    __syncthreads();

    bf16x8 ah[4], al[4], bhf[4], blf[4];
#pragma unroll
    for (int mf = 0; mf < 4; ++mf) {
      const int row = wr * 64 + mf * 16 + arow;
      const int off = row * 32 + ((agrp ^ ((row >> 1) & 3)) << 3);
      ah[mf] = *(const bf16x8*)(lAh + off);
      al[mf] = *(const bf16x8*)(lAl + off);
    }
#pragma unroll
    for (int nf = 0; nf < 4; ++nf) {
      const int row = wc * 64 + nf * 16 + arow;
      const int off = row * 32 + ((agrp ^ ((row >> 1) & 3)) << 3);
      bhf[nf] = *(const bf16x8*)(lBh + off);
      blf[nf] = *(const bf16x8*)(lBl + off);
    }
#pragma unroll
    for (int mf = 0; mf < 4; ++mf)
#pragma unroll
      for (int nf = 0; nf < 4; ++nf) {
        acc[mf][nf] = __builtin_amdgcn_mfma_f32_16x16x32_bf16(ah[mf], bhf[nf], acc[mf][nf], 0, 0, 0);
        acc[mf][nf] = __builtin_amdgcn_mfma_f32_16x16x32_bf16(ah[mf], blf[nf], acc[mf][nf], 0, 0, 0);
        acc[mf][nf] = __builtin_amdgcn_mfma_f32_16x16x32_bf16(al[mf], bhf[nf], acc[mf][nf], 0, 0, 0);
      }
  }

  if constexpr (EPI == 1) {
#pragma unroll
    for (int nf = 0; nf < 4; ++nf) {
      const int cg = c0 + wc * 64 + nf * 16 + arow;
      const float bv = bias[cg];
#pragma unroll
      for (int mf = 0; mf < 4; ++mf) {
#pragma unroll
        for (int ri = 0; ri < 4; ++ri) {
          const int m = m0 + wr * 64 + mf * 16 + agrp * 4 + ri;
          const int bb = m >> 10, n = m & 1023;
          outf[(size_t)bb * (2048 * 768) + (size_t)(1024 + n) * 768 + cg] =
              acc[mf][nf][ri] + bv;
        }
      }
    }
  } else {  // EPI == 2: transposed split (B,H,64,N)
#pragma unroll
    for (int nf = 0; nf < 4; ++nf) {
      const int cg = c0 + wc * 64 + nf * 16 + arow;
      const int h = cg >> 6, d = cg & 63;
      const float bv = bias[cg];
#pragma unroll
      for (int mf = 0; mf < 4; ++mf) {
#pragma unroll
        for (int ri = 0; ri < 4; ++ri) {
          const int m = m0 + wr * 64 + mf * 16 + agrp * 4 + ri;
          const int bb = m >> 10, n = m & 1023;
          unsigned short hi, lo;
          split2(acc[mf][nf][ri] + bv, hi, lo);
          const size_t idx = ((size_t)(bb * HEADS + h) * HD + d) * NSEQ + n;
          vt_hi[idx] = hi;
          vt_lo[idx] = lo;
        }
      }
    }
  }
}

// ---------------------------------------------------------------------------
// Flash attention (split-bf16). K/V staged by global_load_lds with
// pre-swizzled global source; ds_reads use chunk^(row&7) 16B swizzle.
// ---------------------------------------------------------------------------
__global__ __launch_bounds__(256) void attn_single_k(
    const unsigned short* __restrict__ q_hi, const unsigned short* __restrict__ q_lo,
    const unsigned short* __restrict__ k_hi, const unsigned short* __restrict__ k_lo,
    const unsigned short* __restrict__ vt_hi, const unsigned short* __restrict__ vt_lo,
    unsigned short* __restrict__ osph, unsigned short* __restrict__ ospl)
{
  __shared__ __attribute__((aligned(16))) unsigned char lds[50176];
  unsigned char* const ldsK_hi = lds;
  unsigned char* const ldsK_lo = lds + 8192;
  unsigned char* const ldsV_hi = lds + 16384;
  unsigned char* const ldsV_lo = lds + 24576;

  const int tid  = threadIdx.x;
  const int wave = tid >> 6;
  const int lane = tid & 63;

  int flat = blockIdx.x + 16 * blockIdx.y + 192 * blockIdx.z;
  flat = (flat & 7) * 96 + (flat >> 3);
  const int bxq = flat & 15;
  const int h = (flat >> 4) % 12;
  const int b = flat / 192;
  const int bh = b * HEADS + h;
  const int q0 = bxq * 64 + wave * 16;

  unsigned int* const ldsP = (unsigned int*)(lds + 32768) + wave * (16 * 68);

  const int arow = lane & 15;
  const int agrp = lane >> 4;

  bf16x8 qh[2], ql[2];
  {
    const unsigned short* qp = q_hi + ((size_t)bh * NSEQ + q0 + arow) * HD + agrp * 8;
    qh[0] = *(const bf16x8*)qp;
    qh[1] = *(const bf16x8*)(qp + 32);
    const unsigned short* qp2 = q_lo + ((size_t)bh * NSEQ + q0 + arow) * HD + agrp * 8;
    ql[0] = *(const bf16x8*)qp2;
    ql[1] = *(const bf16x8*)(qp2 + 32);
  }

  f32x4 acc[4];
#pragma unroll
  for (int i = 0; i < 4; ++i) acc[i] = f32x4{0.f, 0.f, 0.f, 0.f};
  float m_run[4], l_run[4];
#pragma unroll
  for (int r = 0; r < 4; ++r) { m_run[r] = -3.0e38f; l_run[r] = 0.f; }

  const int sr = tid >> 3, sc = tid & 7;
  const int swzc = ((sc ^ (sr & 7)) << 3);
  const size_t kbase = (size_t)bh * NSEQ * HD;
  const size_t vbase = (size_t)bh * HD * NSEQ;
  const unsigned short* gKh = k_hi + kbase + (size_t)sr * 64 + swzc;
  const unsigned short* gKl = k_lo + kbase + (size_t)sr * 64 + swzc;
  const unsigned short* gVh = vt_hi + vbase + (size_t)sr * NSEQ + swzc;
  const unsigned short* gVl = vt_lo + vbase + (size_t)sr * NSEQ + swzc;
  const int ldsw = (wave * 8) * 128;

  for (int j0 = 0; j0 < NSEQ; j0 += 64) {
    __syncthreads();
    gl16(gKh + j0 * 64, ldsK_hi + ldsw);
    gl16(gKh + j0 * 64 + 2048, ldsK_hi + ldsw + 4096);
    gl16(gKl + j0 * 64, ldsK_lo + ldsw);
    gl16(gKl + j0 * 64 + 2048, ldsK_lo + ldsw + 4096);
    gl16(gVh + j0, ldsV_hi + ldsw);
    gl16(gVh + j0 + 32 * NSEQ, ldsV_hi + ldsw + 4096);
    gl16(gVl + j0, ldsV_lo + ldsw);
    gl16(gVl + j0 + 32 * NSEQ, ldsV_lo + ldsw + 4096);
    __syncthreads();

    f32x4 s[4];
#pragma unroll
    for (int nt = 0; nt < 4; ++nt) s[nt] = f32x4{0.f, 0.f, 0.f, 0.f};
#pragma unroll
    for (int ks = 0; ks < 2; ++ks) {
#pragma unroll
      for (int nt = 0; nt < 4; ++nt) {
        const int krow = nt * 16 + arow;
        const int chunk = ks * 4 + agrp;
        const int off = krow * 128 + (((chunk ^ (krow & 7)) << 4));
        bf16x8 bh_ = *(const bf16x8*)(ldsK_hi + off);
        bf16x8 bl_ = *(const bf16x8*)(ldsK_lo + off);
        s[nt] = __builtin_amdgcn_mfma_f32_16x16x32_bf16(qh[ks], bh_, s[nt], 0, 0, 0);
        s[nt] = __builtin_amdgcn_mfma_f32_16x16x32_bf16(qh[ks], bl_, s[nt], 0, 0, 0);
        s[nt] = __builtin_amdgcn_mfma_f32_16x16x32_bf16(ql[ks], bh_, s[nt], 0, 0, 0);
      }
    }
#pragma unroll
    for (int nt = 0; nt < 4; ++nt) s[nt] *= 0.125f;

    float corr[4], rsum[4];
#pragma unroll
    for (int r = 0; r < 4; ++r) {
      float mx = fmaxf(fmaxf(s[0][r], s[1][r]), fmaxf(s[2][r], s[3][r]));
      mx = fmaxf(mx, __shfl_xor(mx, 1, 64));
      mx = fmaxf(mx, __shfl_xor(mx, 2, 64));
      mx = fmaxf(mx, __shfl_xor(mx, 4, 64));
      mx = fmaxf(mx, __shfl_xor(mx, 8, 64));
      float mnew = fmaxf(m_run[r], mx);
      corr[r] = __expf(m_run[r] - mnew);
      m_run[r] = mnew;
      rsum[r] = 0.f;
    }
#pragma unroll
    for (int nt = 0; nt < 4; ++nt) {
#pragma unroll
      for (int r = 0; r < 4; ++r) {
        float p = __expf(s[nt][r] - m_run[r]);
        rsum[r] += p;
        unsigned short ph, pl;
        split2(p, ph, pl);
        ldsP[(agrp * 4 + r) * 68 + nt * 16 + arow] =
            (unsigned int)ph | ((unsigned int)pl << 16);
      }
    }
#pragma unroll
    for (int r = 0; r < 4; ++r) {
      float sm = rsum[r];
      sm += __shfl_xor(sm, 1, 64);
      sm += __shfl_xor(sm, 2, 64);
      sm += __shfl_xor(sm, 4, 64);
      sm += __shfl_xor(sm, 8, 64);
      l_run[r] = l_run[r] * corr[r] + sm;
#pragma unroll
      for (int nt2 = 0; nt2 < 4; ++nt2) acc[nt2][r] *= corr[r];
    }

#pragma unroll
    for (int kk = 0; kk < 2; ++kk) {
      const unsigned int* prow = ldsP + arow * 68 + kk * 32 + agrp * 8;
      u32x4v w0 = *(const u32x4v*)prow;
      u32x4v w1 = *(const u32x4v*)(prow + 4);
      bf16x8 pa_h, pa_l;
#pragma unroll
      for (int i = 0; i < 4; ++i) {
        pa_h[i]     = (short)(w0[i] & 0xffffu);
        pa_l[i]     = (short)(w0[i] >> 16);
        pa_h[4 + i] = (short)(w1[i] & 0xffffu);
        pa_l[4 + i] = (short)(w1[i] >> 16);
      }
#pragma unroll
      for (int nt2 = 0; nt2 < 4; ++nt2) {
        const int vrow = nt2 * 16 + arow;
        const int chunk = kk * 4 + agrp;
        const int off = vrow * 128 + (((chunk ^ (vrow & 7)) << 4));
        bf16x8 vh_ = *(const bf16x8*)(ldsV_hi + off);
        bf16x8 vl_ = *(const bf16x8*)(ldsV_lo + off);
        acc[nt2] = __builtin_amdgcn_mfma_f32_16x16x32_bf16(pa_h, vh_, acc[nt2], 0, 0, 0);
        acc[nt2] = __builtin_amdgcn_mfma_f32_16x16x32_bf16(pa_h, vl_, acc[nt2], 0, 0, 0);
        acc[nt2] = __builtin_amdgcn_mfma_f32_16x16x32_bf16(pa_l, vh_, acc[nt2], 0, 0, 0);
      }
    }
  }

#pragma unroll
  for (int r = 0; r < 4; ++r) {
    const float inv = 1.f / l_run[r];
    const int n = q0 + agrp * 4 + r;
    const size_t obase = ((size_t)(b * NSEQ + n)) * C_DIM + h * HD + arow;
#pragma unroll
    for (int nt2 = 0; nt2 < 4; ++nt2) {
      unsigned short hi, lo;
      split2(acc[nt2][r] * inv, hi, lo);
      osph[obase + nt2 * 16] = hi;
      ospl[obase + nt2 * 16] = lo;
    }
  }
}

// ---------------------------------------------------------------------------
// Fused attention (steps 4+5): shared QK^T + softmax, two PV passes.
// ---------------------------------------------------------------------------
__global__ __launch_bounds__(256) void attn_fused_k(
    const unsigned short* __restrict__ q_hi, const unsigned short* __restrict__ q_lo,
    const unsigned short* __restrict__ k_hi, const unsigned short* __restrict__ k_lo,
    const unsigned short* __restrict__ vAh_, const unsigned short* __restrict__ vAl_,
    const unsigned short* __restrict__ vBh_, const unsigned short* __restrict__ vBl_,
    float* __restrict__ out1,
    unsigned short* __restrict__ osph, unsigned short* __restrict__ ospl)
{
  __shared__ __attribute__((aligned(16))) unsigned char lds[66560];
  unsigned char* const ldsK_hi = lds;
  unsigned char* const ldsK_lo = lds + 8192;
  unsigned char* const ldsA_hi = lds + 16384;
  unsigned char* const ldsA_lo = lds + 24576;
  unsigned char* const ldsB_hi = lds + 32768;
  unsigned char* const ldsB_lo = lds + 40960;

  const int tid  = threadIdx.x;
  const int wave = tid >> 6;
  const int lane = tid & 63;

  int flat = blockIdx.x + 16 * blockIdx.y + 192 * blockIdx.z;
  flat = (flat & 7) * 96 + (flat >> 3);
  const int bxq = flat & 15;
  const int h = (flat >> 4) % 12;
  const int b = flat / 192;
  const int bh = b * HEADS + h;
  const int q0 = bxq * 64 + wave * 16;

  unsigned int* const ldsP = (unsigned int*)(lds + 49152) + wave * (16 * 68);

  const int arow = lane & 15;
  const int agrp = lane >> 4;

  bf16x8 qh[2], ql[2];
  {
    const unsigned short* qp = q_hi + ((size_t)bh * NSEQ + q0 + arow) * HD + agrp * 8;
    qh[0] = *(const bf16x8*)qp;
    qh[1] = *(const bf16x8*)(qp + 32);
    const unsigned short* qp2 = q_lo + ((size_t)bh * NSEQ + q0 + arow) * HD + agrp * 8;
    ql[0] = *(const bf16x8*)qp2;
    ql[1] = *(const bf16x8*)(qp2 + 32);
  }

  f32x4 acc1[4], acc2[4];
#pragma unroll
  for (int i = 0; i < 4; ++i) {
    acc1[i] = f32x4{0.f, 0.f, 0.f, 0.f};
    acc2[i] = f32x4{0.f, 0.f, 0.f, 0.f};
  }
  float m_run[4], l_run[4];
#pragma unroll
  for (int r = 0; r < 4; ++r) { m_run[r] = -3.0e38f; l_run[r] = 0.f; }

  const int sr = tid >> 3, sc = tid & 7;
  const int swzc = ((sc ^ (sr & 7)) << 3);
  const size_t kbase = (size_t)bh * NSEQ * HD;
  const size_t vbase = (size_t)bh * HD * NSEQ;
  const unsigned short* gKh = k_hi + kbase + (size_t)sr * 64 + swzc;
  const unsigned short* gKl = k_lo + kbase + (size_t)sr * 64 + swzc;
  const unsigned short* gAh = vAh_ + vbase + (size_t)sr * NSEQ + swzc;
  const unsigned short* gAl = vAl_ + vbase + (size_t)sr * NSEQ + swzc;
  const unsigned short* gBh = vBh_ + vbase + (size_t)sr * NSEQ + swzc;
  const unsigned short* gBl = vBl_ + vbase + (size_t)sr * NSEQ + swzc;
  const int ldsw = (wave * 8) * 128;

  for (int j0 = 0; j0 < NSEQ; j0 += 64) {
    __syncthreads();
    gl16(gKh + j0 * 64, ldsK_hi + ldsw);
    gl16(gKh + j0 * 64 + 2048, ldsK_hi + ldsw + 4096);
    gl16(gKl + j0 * 64, ldsK_lo + ldsw);
    gl16(gKl + j0 * 64 + 2048, ldsK_lo + ldsw + 4096);
    gl16(gAh + j0, ldsA_hi + ldsw);
    gl16(gAh + j0 + 32 * NSEQ, ldsA_hi + ldsw + 4096);
    gl16(gAl + j0, ldsA_lo + ldsw);
    gl16(gAl + j0 + 32 * NSEQ, ldsA_lo + ldsw + 4096);
    gl16(gBh + j0, ldsB_hi + ldsw);
    gl16(gBh + j0 + 32 * NSEQ, ldsB_hi + ldsw + 4096);
    gl16(gBl + j0, ldsB_lo + ldsw);
    gl16(gBl + j0 + 32 * NSEQ, ldsB_lo + ldsw + 4096);
    __syncthreads();

    f32x4 s[4];
#pragma unroll
    for (int nt = 0; nt < 4; ++nt) s[nt] = f32x4{0.f, 0.f, 0.f, 0.f};
#pragma unroll
    for (int ks = 0; ks < 2; ++ks) {
#pragma unroll
      for (int nt = 0; nt < 4; ++nt) {
        const int krow = nt * 16 + arow;
        const int chunk = ks * 4 + agrp;
        const int off = krow * 128 + (((chunk ^ (krow & 7)) << 4));
        bf16x8 bh_ = *(const bf16x8*)(ldsK_hi + off);
        bf16x8 bl_ = *(const bf16x8*)(ldsK_lo + off);
        s[nt] = __builtin_amdgcn_mfma_f32_16x16x32_bf16(qh[ks], bh_, s[nt], 0, 0, 0);
        s[nt] = __builtin_amdgcn_mfma_f32_16x16x32_bf16(qh[ks], bl_, s[nt], 0, 0, 0);
        s[nt] = __builtin_amdgcn_mfma_f32_16x16x32_bf16(ql[ks], bh_, s[nt], 0, 0, 0);
      }
    }
#pragma unroll
    for (int nt = 0; nt < 4; ++nt) s[nt] *= 0.125f;

    float corr[4], rsum[4];
#pragma unroll
    for (int r = 0; r < 4; ++r) {
      float mx = fmaxf(fmaxf(s[0][r], s[1][r]), fmaxf(s[2][r], s[3][r]));
      mx = fmaxf(mx, __shfl_xor(mx, 1, 64));
      mx = fmaxf(mx, __shfl_xor(mx, 2, 64));
      mx = fmaxf(mx, __shfl_xor(mx, 4, 64));
      mx = fmaxf(mx, __shfl_xor(mx, 8, 64));
      float mnew = fmaxf(m_run[r], mx);
      corr[r] = __expf(m_run[r] - mnew);
      m_run[r] = mnew;
      rsum[r] = 0.f;
    }
#pragma unroll
    for (int nt = 0; nt < 4; ++nt) {
#pragma unroll
      for (int r = 0; r < 4; ++r) {
        float p = __expf(s[nt][r] - m_run[r]);
        rsum[r] += p;
        unsigned short ph, pl;
        split2(p, ph, pl);
        ldsP[(agrp * 4 + r) * 68 + nt * 16 + arow] =
            (unsigned int)ph | ((unsigned int)pl << 16);
      }
    }
#pragma unroll
    for (int r = 0; r < 4; ++r) {
      float sm = rsum[r];
      sm += __shfl_xor(sm, 1, 64);
      sm += __shfl_xor(sm, 2, 64);
      sm += __shfl_xor(sm, 4, 64);
      sm += __shfl_xor(sm, 8, 64);
      l_run[r] = l_run[r] * corr[r] + sm;
#pragma unroll
      for (int nt2 = 0; nt2 < 4; ++nt2) {
        acc1[nt2][r] *= corr[r];
        acc2[nt2][r] *= corr[r];
      }
    }

#pragma unroll
    for (int kk = 0; kk < 2; ++kk) {
      const unsigned int* prow = ldsP + arow * 68 + kk * 32 + agrp * 8;
      u32x4v w0 = *(const u32x4v*)prow;
      u32x4v w1 = *(const u32x4v*)(prow + 4);
      bf16x8 pa_h, pa_l;
#pragma unroll
      for (int i = 0; i < 4; ++i) {
        pa_h[i]     = (short)(w0[i] & 0xffffu);
        pa_l[i]     = (short)(w0[i] >> 16);
        pa_h[4 + i] = (short)(w1[i] & 0xffffu);
        pa_l[4 + i] = (short)(w1[i] >> 16);
      }
#pragma unroll
      for (int nt2 = 0; nt2 < 4; ++nt2) {
        const int vrow = nt2 * 16 + arow;
        const int chunk = kk * 4 + agrp;
        const int off = vrow * 128 + (((chunk ^ (vrow & 7)) << 4));
        bf16x8 vh_ = *(const bf16x8*)(ldsA_hi + off);
        bf16x8 vl_ = *(const bf16x8*)(ldsA_lo + off);
        acc1[nt2] = __builtin_amdgcn_mfma_f32_16x16x32_bf16(pa_h, vh_, acc1[nt2], 0, 0, 0);
        acc1[nt2] = __builtin_amdgcn_mfma_f32_16x16x32_bf16(pa_h, vl_, acc1[nt2], 0, 0, 0);
        acc1[nt2] = __builtin_amdgcn_mfma_f32_16x16x32_bf16(pa_l, vh_, acc1[nt2], 0, 0, 0);
        bf16x8 uh_ = *(const bf16x8*)(ldsB_hi + off);
        bf16x8 ul_ = *(const bf16x8*)(ldsB_lo + off);
        acc2[nt2] = __builtin_amdgcn_mfma_f32_16x16x32_bf16(pa_h, uh_, acc2[nt2], 0, 0, 0);
        acc2[nt2] = __builtin_amdgcn_mfma_f32_16x16x32_bf16(pa_h, ul_, acc2[nt2], 0, 0, 0);
        acc2[nt2] = __builtin_amdgcn_mfma_f32_16x16x32_bf16(pa_l, uh_, acc2[nt2], 0, 0, 0);
      }
    }
  }

#pragma unroll
  for (int r = 0; r < 4; ++r) {
    const float inv = 1.f / l_run[r];
    const int n = q0 + agrp * 4 + r;
    float* rowp = out1 + (size_t)b * (2048 * C_DIM) + (size_t)n * C_DIM + h * HD + arow;
    const size_t obase = ((size_t)(b * NSEQ + n)) * C_DIM + h * HD + arow;
#pragma unroll
    for (int nt2 = 0; nt2 < 4; ++nt2) {
      rowp[nt2 * 16] = acc1[nt2][r] * inv;
      unsigned short hi, lo;
      split2(acc2[nt2][r] * inv, hi, lo);
      osph[obase + nt2 * 16] = hi;
      ospl[obase + nt2 * 16] = lo;
    }
  }
}

// ---------------------------------------------------------------------------
extern "C" void kernel_launch(void* const* d_in, const int* in_sizes, int n_in,
                              void* d_out, int out_size, void* d_ws, size_t ws_size,
                              hipStream_t stream)
{
  const float* x           = (const float*)d_in[0];
  const float* w_qkv_diff  = (const float*)d_in[1];
  const float* w_qkv_cond  = (const float*)d_in[2];
  const float* w_proj_diff = (const float*)d_in[3];
  const float* b_proj_diff = (const float*)d_in[4];
  const float* w_proj_cond = (const float*)d_in[5];
  const float* b_proj_cond = (const float*)d_in[6];
  float* out = (float*)d_out;

  const size_t SZ = SZC;
  const size_t WQ = 2304 * 768;
  const size_t WP = 768 * 768;
  unsigned short* sw = (unsigned short*)d_ws;
  unsigned short* qd_hi  = sw + 0 * SZ;
  unsigned short* qd_lo  = sw + 1 * SZ;
  unsigned short* kd_hi  = sw + 2 * SZ;
  unsigned short* kd_lo  = sw + 3 * SZ;
  unsigned short* vtd_hi = sw + 4 * SZ;
  unsigned short* vtd_lo = sw + 5 * SZ;
  unsigned short* qc_hi  = sw + 6 * SZ;
  unsigned short* qc_lo  = sw + 7 * SZ;
  unsigned short* kc_hi  = sw + 8 * SZ;
  unsigned short* kc_lo  = sw + 9 * SZ;
  unsigned short* vtc_hi = sw + 10 * SZ;
  unsigned short* vtc_lo = sw + 11 * SZ;
  unsigned short* wqdT_h = sw + 12 * SZ;
  unsigned short* wqdT_l = wqdT_h + WQ;
  unsigned short* wqcT_h = wqdT_l + WQ;
  unsigned short* wqcT_l = wqcT_h + WQ;
  unsigned short* wpdT_h = wqcT_l + WQ;
  unsigned short* wpdT_l = wpdT_h + WP;
  unsigned short* wpcT_h = wpdT_l + WP;
  unsigned short* wpcT_l = wpcT_h + WP;
  unsigned short* osph = wqdT_h;          // aliases wq*T (dead after qkv)
  unsigned short* ospl = wqdT_h + SZ;
  unsigned short* vt2_hi = qd_hi;         // aliases q_d (dead after step 2)
  unsigned short* vt2_lo = qd_lo;

  // 0. weight prep
  split_wT_k<<<dim3(72, 24), dim3(32, 8), 0, stream>>>(w_qkv_diff, 768, 2304, wqdT_h, wqdT_l);
  split_wT_k<<<dim3(72, 24), dim3(32, 8), 0, stream>>>(w_qkv_cond, 768, 2304, wqcT_h, wqcT_l);
  split_wT_k<<<dim3(24, 24), dim3(32, 8), 0, stream>>>(w_proj_diff, 768, 768, wpdT_h, wpdT_l);
  split_wT_k<<<dim3(24, 24), dim3(32, 8), 0, stream>>>(w_proj_cond, 768, 768, wpcT_h, wpcT_l);

  // 1. qkv both streams
  qkv_gemm_k<<<dim3(18, 32, 2), 256, 0, stream>>>(
      x, wqdT_h, wqdT_l, wqcT_h, wqcT_l, sw);

  // 2. attn_diff -> osp split
  attn_single_k<<<dim3(16, 12, 4), 256, 0, stream>>>(
      qd_hi, qd_lo, kd_hi, kd_lo, vtd_hi, vtd_lo, osph, ospl);

  // 3. (osp @ w_proj_diff + b)^T split -> vt2
  proj_gemm_k<2><<<dim3(6, 32), 256, 0, stream>>>(
      osph, ospl, wpdT_h, wpdT_l, b_proj_diff, nullptr, vt2_hi, vt2_lo);

  // 4+5. fused attn_cond: P @ vt2 -> out[:, :N] fp32 ; P @ vt_c -> osp split
  attn_fused_k<<<dim3(16, 12, 4), 256, 0, stream>>>(
      qc_hi, qc_lo, kc_hi, kc_lo, vt2_hi, vt2_lo, vtc_hi, vtc_lo, out, osph, ospl);

  // 6. out[:, N:] = osp @ w_proj_cond + b
  proj_gemm_k<1><<<dim3(6, 32), 256, 0, stream>>>(
      osph, ospl, wpcT_h, wpcT_l, b_proj_cond, out, nullptr, nullptr);
}

// Round 6
// 377.388 us; speedup vs baseline: 8.4292x; 1.0307x over previous
//
#include <hip/hip_runtime.h>
#include <hip/hip_bf16.h>

// B=4, N0=2048 (N=1024 diff + 1024 cond), C=768, H=12, hd=64. All fp32 I/O.
// Split-bf16 (x = hi + lo, 3 bf16-MFMA terms) for all GEMM/attention math.
//   0. weight prep: wT[n][k] split hi/lo for all 4 weight matrices
//   1. qkv both streams  [MFMA] -> split q/k (B,H,N,64) + vt (B,H,64,N) hi/lo
//   2. osp = attn(q_d,k_d,vt_d)              [MFMA] -> SPLIT (B*N,768) hi/lo
//   3. vt2 = (osp @ w_proj_diff + b)^T split [MFMA] -> (B,H,64,N) hi/lo
//   4+5 fused: P = softmax(q_c k_c^T) once;
//        out[:, :N] = P @ vt2 (fp32), osp = P @ vt_c (split)
//   6. out[:, N:] = osp @ w_proj_cond + b    [MFMA]
//
// GEMMs: 2-phase double-buffered pipeline (T3-min): one raw s_barrier +
// manual vmcnt per K-step; prefetch gl16s stay in flight across compute.
// LDS swizzle chunk^((row>>1)&3) both sides (verified 0 conflicts in R5).

#define C_DIM 768
#define HEADS 12
#define HD 64
#define NSEQ 1024
#define BATCH 4
#define SZC 3145728  // BATCH*HEADS*NSEQ*HD

typedef short bf16x8 __attribute__((ext_vector_type(8)));
typedef float f32x4 __attribute__((ext_vector_type(4)));
typedef unsigned int u32x4v __attribute__((ext_vector_type(4)));

typedef __attribute__((address_space(3))) unsigned int lds_u32_t;
typedef __attribute__((address_space(1))) const unsigned int glb_u32_t;

__device__ __forceinline__ void gl16(const void* g, void* l) {
  __builtin_amdgcn_global_load_lds((glb_u32_t*)g, (lds_u32_t*)l, 16, 0, 0);
}

__device__ __forceinline__ unsigned short f2bf(float x) {
  __hip_bfloat16 h = __float2bfloat16(x);
  return *reinterpret_cast<unsigned short*>(&h);
}
__device__ __forceinline__ float bf2f(unsigned short u) {
  __hip_bfloat16 h = *reinterpret_cast<__hip_bfloat16*>(&u);
  return __bfloat162float(h);
}
__device__ __forceinline__ void split2(float x, unsigned short& hi, unsigned short& lo) {
  unsigned short h = f2bf(x);
  lo = f2bf(x - bf2f(h));
  hi = h;
}

// ---------------------------------------------------------------------------
// Weight prep: w (K x N fp32, row-major) -> wT hi/lo (N x K bf16 split).
// ---------------------------------------------------------------------------
__global__ __launch_bounds__(256) void split_wT_k(
    const float* __restrict__ w, int K, int N,
    unsigned short* __restrict__ th, unsigned short* __restrict__ tl)
{
  __shared__ float T[32][33];
  const int n0 = blockIdx.x * 32, k0 = blockIdx.y * 32;
  const int tx = threadIdx.x, ty = threadIdx.y;
#pragma unroll
  for (int i = 0; i < 4; ++i) {
    int k = ty + i * 8;
    T[k][tx] = w[(size_t)(k0 + k) * N + n0 + tx];
  }
  __syncthreads();
#pragma unroll
  for (int i = 0; i < 4; ++i) {
    int n = ty + i * 8;
    float v = T[tx][n];
    unsigned short hi, lo;
    split2(v, hi, lo);
    th[(size_t)(n0 + n) * K + k0 + tx] = hi;
    tl[(size_t)(n0 + n) * K + k0 + tx] = lo;
  }
}

// ---------------------------------------------------------------------------
// QKV GEMM, 2-phase dbuf. A = x fp32: global->reg load issued with prefetch,
// split+ds_write AFTER the MFMA phase (T14 issue-early/write-late).
// B = pre-split weights via gl16 (pre-swizzled source). 128x128, BK=32.
// LDS 64 KB (2 x 32 KB buffers: Ah@0 Al@4096 Bh@8192 Bl@12288 ushorts).
// ---------------------------------------------------------------------------
__global__ __launch_bounds__(256) void qkv_gemm_k(
    const float* __restrict__ x,
    const unsigned short* __restrict__ wdh, const unsigned short* __restrict__ wdl,
    const unsigned short* __restrict__ wch, const unsigned short* __restrict__ wcl,
    unsigned short* __restrict__ ws_split)
{
  __shared__ __attribute__((aligned(16))) unsigned short lds[32768];  // 64 KB

  const int tid = threadIdx.x;
  const int lane = tid & 63;
  const int wave = tid >> 6;
  const int wr = wave >> 1, wc = wave & 1;
  const int arow = lane & 15, agrp = lane >> 4;

  // XCD-aware bijective swizzle: nwg = 1152, /8 = 144
  int flat = blockIdx.x + 18 * blockIdx.y + 576 * blockIdx.z;
  flat = (flat & 7) * 144 + (flat >> 3);
  const int bx = flat % 18;
  const int by = (flat / 18) & 31;
  const int half = flat / 576;

  const int m0 = by * 128;
  const int b = m0 >> 10, nloc = m0 & 1023;
  const int c0 = bx * 128;
  const unsigned short* __restrict__ BTh = half ? wch : wdh;
  const unsigned short* __restrict__ BTl = half ? wcl : wdl;
  const float* __restrict__ Abase = x + (size_t)(b * 2048 + half * 1024 + nloc) * 768;

  const int gr = tid >> 2, gc = (tid & 3) ^ ((tid >> 3) & 3);
  const unsigned short* gBh = BTh + (size_t)(c0 + gr) * 768 + gc * 8;
  const unsigned short* gBl = BTl + (size_t)(c0 + gr) * 768 + gc * 8;
  const int wo = wave * 512;                      // gl16 dest (ushort offset)
  const int ar_ = tid >> 2, ac_ = tid & 3;
  const int aswz = (ac_ ^ ((ar_ >> 1) & 3)) * 8;  // swizzled A chunk slot

  f32x4 acc[4][4];
#pragma unroll
  for (int i = 0; i < 4; ++i)
#pragma unroll
    for (int j = 0; j < 4; ++j) acc[i][j] = f32x4{0.f, 0.f, 0.f, 0.f};

  float4 fA[2][2];

  auto stageB = [&](int k0, int bo) {
    unsigned short* dh = lds + bo + 8192 + wo;
    unsigned short* dl = lds + bo + 12288 + wo;
    gl16(gBh + k0, dh);
    gl16(gBh + k0 + 64 * 768, dh + 2048);
    gl16(gBl + k0, dl);
    gl16(gBl + k0 + 64 * 768, dl + 2048);
  };
  auto loadA = [&](int k0) {
#pragma unroll
    for (int it = 0; it < 2; ++it) {
      const float* p = Abase + (size_t)(it * 64 + ar_) * 768 + k0 + ac_ * 8;
      fA[it][0] = *(const float4*)p;
      fA[it][1] = *(const float4*)(p + 4);
    }
  };
  auto writeA = [&](int bo) {
#pragma unroll
    for (int it = 0; it < 2; ++it) {
      float fa[8] = {fA[it][0].x, fA[it][0].y, fA[it][0].z, fA[it][0].w,
                     fA[it][1].x, fA[it][1].y, fA[it][1].z, fA[it][1].w};
      unsigned short hv[8], lv[8];
#pragma unroll
      for (int j = 0; j < 8; ++j) split2(fa[j], hv[j], lv[j]);
      const int off = (it * 64 + ar_) * 32 + aswz;
      *(bf16x8*)(lds + bo + off) = *(bf16x8*)hv;
      *(bf16x8*)(lds + bo + 4096 + off) = *(bf16x8*)lv;
    }
  };

  // prologue: tile 0 into buf0
  stageB(0, 0);
  loadA(0);
  writeA(0);
  asm volatile("s_waitcnt vmcnt(0) lgkmcnt(0)" ::: "memory");
  __builtin_amdgcn_s_barrier();

  int cur = 0;
  for (int t = 0; t < 24; ++t) {
    const int bo = cur * 16384;
    const int nbo = bo ^ 16384;
    if (t < 23) {                      // issue prefetch for tile t+1
      stageB((t + 1) * 32, nbo);
      loadA((t + 1) * 32);
    }

    bf16x8 ah[4], al[4], bhf[4], blf[4];
#pragma unroll
    for (int mf = 0; mf < 4; ++mf) {
      const int row = wr * 64 + mf * 16 + arow;
      const int off = bo + row * 32 + ((agrp ^ ((row >> 1) & 3)) << 3);
      ah[mf] = *(const bf16x8*)(lds + off);
      al[mf] = *(const bf16x8*)(lds + 4096 + off);
    }
#pragma unroll
    for (int nf = 0; nf < 4; ++nf) {
      const int row = wc * 64 + nf * 16 + arow;
      const int off = bo + row * 32 + ((agrp ^ ((row >> 1) & 3)) << 3);
      bhf[nf] = *(const bf16x8*)(lds + 8192 + off);
      blf[nf] = *(const bf16x8*)(lds + 12288 + off);
    }
#pragma unroll
    for (int mf = 0; mf < 4; ++mf)
#pragma unroll
      for (int nf = 0; nf < 4; ++nf) {
        acc[mf][nf] = __builtin_amdgcn_mfma_f32_16x16x32_bf16(ah[mf], bhf[nf], acc[mf][nf], 0, 0, 0);
        acc[mf][nf] = __builtin_amdgcn_mfma_f32_16x16x32_bf16(ah[mf], blf[nf], acc[mf][nf], 0, 0, 0);
        acc[mf][nf] = __builtin_amdgcn_mfma_f32_16x16x32_bf16(al[mf], bhf[nf], acc[mf][nf], 0, 0, 0);
      }

    if (t < 23) {
      writeA(nbo);                     // split lands after MFMA phase
      asm volatile("s_waitcnt vmcnt(0) lgkmcnt(0)" ::: "memory");
      __builtin_amdgcn_s_barrier();
      cur ^= 1;
    }
  }

  // epilogue: scatter split q/k (row-major) and v (transposed)
#pragma unroll
  for (int nf = 0; nf < 4; ++nf) {
    const int cg = c0 + wc * 64 + nf * 16 + arow;
    const int t = cg / 768;
    const int rem = cg - t * 768;
    const int h = rem >> 6;
    const int d = rem & 63;
    unsigned short* hi_arr = ws_split + (size_t)(half * 6 + t * 2) * SZC;
    unsigned short* lo_arr = hi_arr + SZC;
    const size_t bh_ = (size_t)(b * HEADS + h);
#pragma unroll
    for (int mf = 0; mf < 4; ++mf) {
#pragma unroll
      for (int ri = 0; ri < 4; ++ri) {
        const int n = nloc + wr * 64 + mf * 16 + agrp * 4 + ri;
        unsigned short hi, lo;
        split2(acc[mf][nf][ri], hi, lo);
        size_t idx;
        if (t < 2) idx = (bh_ * NSEQ + n) * HD + d;
        else       idx = (bh_ * HD + d) * NSEQ + n;
        hi_arr[idx] = hi;
        lo_arr[idx] = lo;
      }
    }
  }
}

// ---------------------------------------------------------------------------
// Proj GEMM, 2-phase dbuf, all-gl16 both sides (pre-swizzled sources).
// LDS 64 KB. EPI 1: fp32 d_out[:, N:] + bias. EPI 2: vt2 transposed split.
// ---------------------------------------------------------------------------
template <int EPI>
__global__ __launch_bounds__(256) void proj_gemm_k(
    const unsigned short* __restrict__ Ah, const unsigned short* __restrict__ Al,
    const unsigned short* __restrict__ Bh, const unsigned short* __restrict__ Bl,
    const float* __restrict__ bias,
    float* __restrict__ outf,
    unsigned short* __restrict__ vt_hi, unsigned short* __restrict__ vt_lo)
{
  __shared__ __attribute__((aligned(16))) unsigned short lds[32768];  // 64 KB

  const int tid = threadIdx.x;
  const int lane = tid & 63;
  const int wave = tid >> 6;
  const int wr = wave >> 1, wc = wave & 1;
  const int arow = lane & 15, agrp = lane >> 4;

  int flat = blockIdx.x + 6 * blockIdx.y;
  flat = (flat & 7) * 24 + (flat >> 3);
  const int bx = flat % 6;
  const int by = flat / 6;
  const int m0 = by * 128;
  const int c0 = bx * 128;

  const int gr = tid >> 2, gc = (tid & 3) ^ ((tid >> 3) & 3);
  const unsigned short* gAh = Ah + (size_t)(m0 + gr) * 768 + gc * 8;
  const unsigned short* gAl = Al + (size_t)(m0 + gr) * 768 + gc * 8;
  const unsigned short* gBh = Bh + (size_t)(c0 + gr) * 768 + gc * 8;
  const unsigned short* gBl = Bl + (size_t)(c0 + gr) * 768 + gc * 8;
  const int wo = wave * 512;

  f32x4 acc[4][4];
#pragma unroll
  for (int i = 0; i < 4; ++i)
#pragma unroll
    for (int j = 0; j < 4; ++j) acc[i][j] = f32x4{0.f, 0.f, 0.f, 0.f};

  auto stage8 = [&](int k0, int bo) {
    gl16(gAh + k0, lds + bo + wo);
    gl16(gAh + k0 + 64 * 768, lds + bo + wo + 2048);
    gl16(gAl + k0, lds + bo + 4096 + wo);
    gl16(gAl + k0 + 64 * 768, lds + bo + 4096 + wo + 2048);
    gl16(gBh + k0, lds + bo + 8192 + wo);
    gl16(gBh + k0 + 64 * 768, lds + bo + 8192 + wo + 2048);
    gl16(gBl + k0, lds + bo + 12288 + wo);
    gl16(gBl + k0 + 64 * 768, lds + bo + 12288 + wo + 2048);
  };

  stage8(0, 0);
  asm volatile("s_waitcnt vmcnt(0)" ::: "memory");
  __builtin_amdgcn_s_barrier();

  int cur = 0;
  for (int t = 0; t < 24; ++t) {
    const int bo = cur * 16384;
    const int nbo = bo ^ 16384;
    if (t < 23) stage8((t + 1) * 32, nbo);

    bf16x8 ah[4], al[4], bhf[4], blf[4];
#pragma unroll
    for (int mf = 0; mf < 4; ++mf) {
      const int row = wr * 64 + mf * 16 + arow;
      const int off = bo + row * 32 + ((agrp ^ ((row >> 1) & 3)) << 3);
      ah[mf] = *(const bf16x8*)(lds + off);
      al[mf] = *(const bf16x8*)(lds + 4096 + off);
    }
#pragma unroll
    for (int nf = 0; nf < 4; ++nf) {
      const int row = wc * 64 + nf * 16 + arow;
      const int off = bo + row * 32 + ((agrp ^ ((row >> 1) & 3)) << 3);
      bhf[nf] = *(const bf16x8*)(lds + 8192 + off);
      blf[nf] = *(const bf16x8*)(lds + 12288 + off);
    }
#pragma unroll
    for (int mf = 0; mf < 4; ++mf)
#pragma unroll
      for (int nf = 0; nf < 4; ++nf) {
        acc[mf][nf] = __builtin_amdgcn_mfma_f32_16x16x32_bf16(ah[mf], bhf[nf], acc[mf][nf], 0, 0, 0);
        acc[mf][nf] = __builtin_amdgcn_mfma_f32_16x16x32_bf16(ah[mf], blf[nf], acc[mf][nf], 0, 0, 0);
        acc[mf][nf] = __builtin_amdgcn_mfma_f32_16x16x32_bf16(al[mf], bhf[nf], acc[mf][nf], 0, 0, 0);
      }

    if (t < 23) {
      asm volatile("s_waitcnt vmcnt(0)" ::: "memory");
      __builtin_amdgcn_s_barrier();
      cur ^= 1;
    }
  }

  if constexpr (EPI == 1) {
#pragma unroll
    for (int nf = 0; nf < 4; ++nf) {
      const int cg = c0 + wc * 64 + nf * 16 + arow;
      const float bv = bias[cg];
#pragma unroll
      for (int mf = 0; mf < 4; ++mf) {
#pragma unroll
        for (int ri = 0; ri < 4; ++ri) {
          const int m = m0 + wr * 64 + mf * 16 + agrp * 4 + ri;
          const int bb = m >> 10, n = m & 1023;
          outf[(size_t)bb * (2048 * 768) + (size_t)(1024 + n) * 768 + cg] =
              acc[mf][nf][ri] + bv;
        }
      }
    }
  } else {  // EPI == 2: transposed split (B,H,64,N)
#pragma unroll
    for (int nf = 0; nf < 4; ++nf) {
      const int cg = c0 + wc * 64 + nf * 16 + arow;
      const int h = cg >> 6, d = cg & 63;
      const float bv = bias[cg];
#pragma unroll
      for (int mf = 0; mf < 4; ++mf) {
#pragma unroll
        for (int ri = 0; ri < 4; ++ri) {
          const int m = m0 + wr * 64 + mf * 16 + agrp * 4 + ri;
          const int bb = m >> 10, n = m & 1023;
          unsigned short hi, lo;
          split2(acc[mf][nf][ri] + bv, hi, lo);
          const size_t idx = ((size_t)(bb * HEADS + h) * HD + d) * NSEQ + n;
          vt_hi[idx] = hi;
          vt_lo[idx] = lo;
        }
      }
    }
  }
}

// ---------------------------------------------------------------------------
// Flash attention (split-bf16), unchanged from R5 (proven).
// ---------------------------------------------------------------------------
__global__ __launch_bounds__(256) void attn_single_k(
    const unsigned short* __restrict__ q_hi, const unsigned short* __restrict__ q_lo,
    const unsigned short* __restrict__ k_hi, const unsigned short* __restrict__ k_lo,
    const unsigned short* __restrict__ vt_hi, const unsigned short* __restrict__ vt_lo,
    unsigned short* __restrict__ osph, unsigned short* __restrict__ ospl)
{
  __shared__ __attribute__((aligned(16))) unsigned char lds[50176];
  unsigned char* const ldsK_hi = lds;
  unsigned char* const ldsK_lo = lds + 8192;
  unsigned char* const ldsV_hi = lds + 16384;
  unsigned char* const ldsV_lo = lds + 24576;

  const int tid  = threadIdx.x;
  const int wave = tid >> 6;
  const int lane = tid & 63;

  int flat = blockIdx.x + 16 * blockIdx.y + 192 * blockIdx.z;
  flat = (flat & 7) * 96 + (flat >> 3);
  const int bxq = flat & 15;
  const int h = (flat >> 4) % 12;
  const int b = flat / 192;
  const int bh = b * HEADS + h;
  const int q0 = bxq * 64 + wave * 16;

  unsigned int* const ldsP = (unsigned int*)(lds + 32768) + wave * (16 * 68);

  const int arow = lane & 15;
  const int agrp = lane >> 4;

  bf16x8 qh[2], ql[2];
  {
    const unsigned short* qp = q_hi + ((size_t)bh * NSEQ + q0 + arow) * HD + agrp * 8;
    qh[0] = *(const bf16x8*)qp;
    qh[1] = *(const bf16x8*)(qp + 32);
    const unsigned short* qp2 = q_lo + ((size_t)bh * NSEQ + q0 + arow) * HD + agrp * 8;
    ql[0] = *(const bf16x8*)qp2;
    ql[1] = *(const bf16x8*)(qp2 + 32);
  }

  f32x4 acc[4];
#pragma unroll
  for (int i = 0; i < 4; ++i) acc[i] = f32x4{0.f, 0.f, 0.f, 0.f};
  float m_run[4], l_run[4];
#pragma unroll
  for (int r = 0; r < 4; ++r) { m_run[r] = -3.0e38f; l_run[r] = 0.f; }

  const int sr = tid >> 3, sc = tid & 7;
  const int swzc = ((sc ^ (sr & 7)) << 3);
  const size_t kbase = (size_t)bh * NSEQ * HD;
  const size_t vbase = (size_t)bh * HD * NSEQ;
  const unsigned short* gKh = k_hi + kbase + (size_t)sr * 64 + swzc;
  const unsigned short* gKl = k_lo + kbase + (size_t)sr * 64 + swzc;
  const unsigned short* gVh = vt_hi + vbase + (size_t)sr * NSEQ + swzc;
  const unsigned short* gVl = vt_lo + vbase + (size_t)sr * NSEQ + swzc;
  const int ldsw = (wave * 8) * 128;

  for (int j0 = 0; j0 < NSEQ; j0 += 64) {
    __syncthreads();
    gl16(gKh + j0 * 64, ldsK_hi + ldsw);
    gl16(gKh + j0 * 64 + 2048, ldsK_hi + ldsw + 4096);
    gl16(gKl + j0 * 64, ldsK_lo + ldsw);
    gl16(gKl + j0 * 64 + 2048, ldsK_lo + ldsw + 4096);
    gl16(gVh + j0, ldsV_hi + ldsw);
    gl16(gVh + j0 + 32 * NSEQ, ldsV_hi + ldsw + 4096);
    gl16(gVl + j0, ldsV_lo + ldsw);
    gl16(gVl + j0 + 32 * NSEQ, ldsV_lo + ldsw + 4096);
    __syncthreads();

    f32x4 s[4];
#pragma unroll
    for (int nt = 0; nt < 4; ++nt) s[nt] = f32x4{0.f, 0.f, 0.f, 0.f};
#pragma unroll
    for (int ks = 0; ks < 2; ++ks) {
#pragma unroll
      for (int nt = 0; nt < 4; ++nt) {
        const int krow = nt * 16 + arow;
        const int chunk = ks * 4 + agrp;
        const int off = krow * 128 + (((chunk ^ (krow & 7)) << 4));
        bf16x8 bh_ = *(const bf16x8*)(ldsK_hi + off);
        bf16x8 bl_ = *(const bf16x8*)(ldsK_lo + off);
        s[nt] = __builtin_amdgcn_mfma_f32_16x16x32_bf16(qh[ks], bh_, s[nt], 0, 0, 0);
        s[nt] = __builtin_amdgcn_mfma_f32_16x16x32_bf16(qh[ks], bl_, s[nt], 0, 0, 0);
        s[nt] = __builtin_amdgcn_mfma_f32_16x16x32_bf16(ql[ks], bh_, s[nt], 0, 0, 0);
      }
    }
#pragma unroll
    for (int nt = 0; nt < 4; ++nt) s[nt] *= 0.125f;

    float corr[4], rsum[4];
#pragma unroll
    for (int r = 0; r < 4; ++r) {
      float mx = fmaxf(fmaxf(s[0][r], s[1][r]), fmaxf(s[2][r], s[3][r]));
      mx = fmaxf(mx, __shfl_xor(mx, 1, 64));
      mx = fmaxf(mx, __shfl_xor(mx, 2, 64));
      mx = fmaxf(mx, __shfl_xor(mx, 4, 64));
      mx = fmaxf(mx, __shfl_xor(mx, 8, 64));
      float mnew = fmaxf(m_run[r], mx);
      corr[r] = __expf(m_run[r] - mnew);
      m_run[r] = mnew;
      rsum[r] = 0.f;
    }
#pragma unroll
    for (int nt = 0; nt < 4; ++nt) {
#pragma unroll
      for (int r = 0; r < 4; ++r) {
        float p = __expf(s[nt][r] - m_run[r]);
        rsum[r] += p;
        unsigned short ph, pl;
        split2(p, ph, pl);
        ldsP[(agrp * 4 + r) * 68 + nt * 16 + arow] =
            (unsigned int)ph | ((unsigned int)pl << 16);
      }
    }
#pragma unroll
    for (int r = 0; r < 4; ++r) {
      float sm = rsum[r];
      sm += __shfl_xor(sm, 1, 64);
      sm += __shfl_xor(sm, 2, 64);
      sm += __shfl_xor(sm, 4, 64);
      sm += __shfl_xor(sm, 8, 64);
      l_run[r] = l_run[r] * corr[r] + sm;
#pragma unroll
      for (int nt2 = 0; nt2 < 4; ++nt2) acc[nt2][r] *= corr[r];
    }

#pragma unroll
    for (int kk = 0; kk < 2; ++kk) {
      const unsigned int* prow = ldsP + arow * 68 + kk * 32 + agrp * 8;
      u32x4v w0 = *(const u32x4v*)prow;
      u32x4v w1 = *(const u32x4v*)(prow + 4);
      bf16x8 pa_h, pa_l;
#pragma unroll
      for (int i = 0; i < 4; ++i) {
        pa_h[i]     = (short)(w0[i] & 0xffffu);
        pa_l[i]     = (short)(w0[i] >> 16);
        pa_h[4 + i] = (short)(w1[i] & 0xffffu);
        pa_l[4 + i] = (short)(w1[i] >> 16);
      }
#pragma unroll
      for (int nt2 = 0; nt2 < 4; ++nt2) {
        const int vrow = nt2 * 16 + arow;
        const int chunk = kk * 4 + agrp;
        const int off = vrow * 128 + (((chunk ^ (vrow & 7)) << 4));
        bf16x8 vh_ = *(const bf16x8*)(ldsV_hi + off);
        bf16x8 vl_ = *(const bf16x8*)(ldsV_lo + off);
        acc[nt2] = __builtin_amdgcn_mfma_f32_16x16x32_bf16(pa_h, vh_, acc[nt2], 0, 0, 0);
        acc[nt2] = __builtin_amdgcn_mfma_f32_16x16x32_bf16(pa_h, vl_, acc[nt2], 0, 0, 0);
        acc[nt2] = __builtin_amdgcn_mfma_f32_16x16x32_bf16(pa_l, vh_, acc[nt2], 0, 0, 0);
      }
    }
  }

#pragma unroll
  for (int r = 0; r < 4; ++r) {
    const float inv = 1.f / l_run[r];
    const int n = q0 + agrp * 4 + r;
    const size_t obase = ((size_t)(b * NSEQ + n)) * C_DIM + h * HD + arow;
#pragma unroll
    for (int nt2 = 0; nt2 < 4; ++nt2) {
      unsigned short hi, lo;
      split2(acc[nt2][r] * inv, hi, lo);
      osph[obase + nt2 * 16] = hi;
      ospl[obase + nt2 * 16] = lo;
    }
  }
}

// ---------------------------------------------------------------------------
// Fused attention (steps 4+5), unchanged from R5 (proven).
// ---------------------------------------------------------------------------
__global__ __launch_bounds__(256) void attn_fused_k(
    const unsigned short* __restrict__ q_hi, const unsigned short* __restrict__ q_lo,
    const unsigned short* __restrict__ k_hi, const unsigned short* __restrict__ k_lo,
    const unsigned short* __restrict__ vAh_, const unsigned short* __restrict__ vAl_,
    const unsigned short* __restrict__ vBh_, const unsigned short* __restrict__ vBl_,
    float* __restrict__ out1,
    unsigned short* __restrict__ osph, unsigned short* __restrict__ ospl)
{
  __shared__ __attribute__((aligned(16))) unsigned char lds[66560];
  unsigned char* const ldsK_hi = lds;
  unsigned char* const ldsK_lo = lds + 8192;
  unsigned char* const ldsA_hi = lds + 16384;
  unsigned char* const ldsA_lo = lds + 24576;
  unsigned char* const ldsB_hi = lds + 32768;
  unsigned char* const ldsB_lo = lds + 40960;

  const int tid  = threadIdx.x;
  const int wave = tid >> 6;
  const int lane = tid & 63;

  int flat = blockIdx.x + 16 * blockIdx.y + 192 * blockIdx.z;
  flat = (flat & 7) * 96 + (flat >> 3);
  const int bxq = flat & 15;
  const int h = (flat >> 4) % 12;
  const int b = flat / 192;
  const int bh = b * HEADS + h;
  const int q0 = bxq * 64 + wave * 16;

  unsigned int* const ldsP = (unsigned int*)(lds + 49152) + wave * (16 * 68);

  const int arow = lane & 15;
  const int agrp = lane >> 4;

  bf16x8 qh[2], ql[2];
  {
    const unsigned short* qp = q_hi + ((size_t)bh * NSEQ + q0 + arow) * HD + agrp * 8;
    qh[0] = *(const bf16x8*)qp;
    qh[1] = *(const bf16x8*)(qp + 32);
    const unsigned short* qp2 = q_lo + ((size_t)bh * NSEQ + q0 + arow) * HD + agrp * 8;
    ql[0] = *(const bf16x8*)qp2;
    ql[1] = *(const bf16x8*)(qp2 + 32);
  }

  f32x4 acc1[4], acc2[4];
#pragma unroll
  for (int i = 0; i < 4; ++i) {
    acc1[i] = f32x4{0.f, 0.f, 0.f, 0.f};
    acc2[i] = f32x4{0.f, 0.f, 0.f, 0.f};
  }
  float m_run[4], l_run[4];
#pragma unroll
  for (int r = 0; r < 4; ++r) { m_run[r] = -3.0e38f; l_run[r] = 0.f; }

  const int sr = tid >> 3, sc = tid & 7;
  const int swzc = ((sc ^ (sr & 7)) << 3);
  const size_t kbase = (size_t)bh * NSEQ * HD;
  const size_t vbase = (size_t)bh * HD * NSEQ;
  const unsigned short* gKh = k_hi + kbase + (size_t)sr * 64 + swzc;
  const unsigned short* gKl = k_lo + kbase + (size_t)sr * 64 + swzc;
  const unsigned short* gAh = vAh_ + vbase + (size_t)sr * NSEQ + swzc;
  const unsigned short* gAl = vAl_ + vbase + (size_t)sr * NSEQ + swzc;
  const unsigned short* gBh = vBh_ + vbase + (size_t)sr * NSEQ + swzc;
  const unsigned short* gBl = vBl_ + vbase + (size_t)sr * NSEQ + swzc;
  const int ldsw = (wave * 8) * 128;

  for (int j0 = 0; j0 < NSEQ; j0 += 64) {
    __syncthreads();
    gl16(gKh + j0 * 64, ldsK_hi + ldsw);
    gl16(gKh + j0 * 64 + 2048, ldsK_hi + ldsw + 4096);
    gl16(gKl + j0 * 64, ldsK_lo + ldsw);
    gl16(gKl + j0 * 64 + 2048, ldsK_lo + ldsw + 4096);
    gl16(gAh + j0, ldsA_hi + ldsw);
    gl16(gAh + j0 + 32 * NSEQ, ldsA_hi + ldsw + 4096);
    gl16(gAl + j0, ldsA_lo + ldsw);
    gl16(gAl + j0 + 32 * NSEQ, ldsA_lo + ldsw + 4096);
    gl16(gBh + j0, ldsB_hi + ldsw);
    gl16(gBh + j0 + 32 * NSEQ, ldsB_hi + ldsw + 4096);
    gl16(gBl + j0, ldsB_lo + ldsw);
    gl16(gBl + j0 + 32 * NSEQ, ldsB_lo + ldsw + 4096);
    __syncthreads();

    f32x4 s[4];
#pragma unroll
    for (int nt = 0; nt < 4; ++nt) s[nt] = f32x4{0.f, 0.f, 0.f, 0.f};
#pragma unroll
    for (int ks = 0; ks < 2; ++ks) {
#pragma unroll
      for (int nt = 0; nt < 4; ++nt) {
        const int krow = nt * 16 + arow;
        const int chunk = ks * 4 + agrp;
        const int off = krow * 128 + (((chunk ^ (krow & 7)) << 4));
        bf16x8 bh_ = *(const bf16x8*)(ldsK_hi + off);
        bf16x8 bl_ = *(const bf16x8*)(ldsK_lo + off);
        s[nt] = __builtin_amdgcn_mfma_f32_16x16x32_bf16(qh[ks], bh_, s[nt], 0, 0, 0);
        s[nt] = __builtin_amdgcn_mfma_f32_16x16x32_bf16(qh[ks], bl_, s[nt], 0, 0, 0);
        s[nt] = __builtin_amdgcn_mfma_f32_16x16x32_bf16(ql[ks], bh_, s[nt], 0, 0, 0);
      }
    }
#pragma unroll
    for (int nt = 0; nt < 4; ++nt) s[nt] *= 0.125f;

    float corr[4], rsum[4];
#pragma unroll
    for (int r = 0; r < 4; ++r) {
      float mx = fmaxf(fmaxf(s[0][r], s[1][r]), fmaxf(s[2][r], s[3][r]));
      mx = fmaxf(mx, __shfl_xor(mx, 1, 64));
      mx = fmaxf(mx, __shfl_xor(mx, 2, 64));
      mx = fmaxf(mx, __shfl_xor(mx, 4, 64));
      mx = fmaxf(mx, __shfl_xor(mx, 8, 64));
      float mnew = fmaxf(m_run[r], mx);
      corr[r] = __expf(m_run[r] - mnew);
      m_run[r] = mnew;
      rsum[r] = 0.f;
    }
#pragma unroll
    for (int nt = 0; nt < 4; ++nt) {
#pragma unroll
      for (int r = 0; r < 4; ++r) {
        float p = __expf(s[nt][r] - m_run[r]);
        rsum[r] += p;
        unsigned short ph, pl;
        split2(p, ph, pl);
        ldsP[(agrp * 4 + r) * 68 + nt * 16 + arow] =
            (unsigned int)ph | ((unsigned int)pl << 16);
      }
    }
#pragma unroll
    for (int r = 0; r < 4; ++r) {
      float sm = rsum[r];
      sm += __shfl_xor(sm, 1, 64);
      sm += __shfl_xor(sm, 2, 64);
      sm += __shfl_xor(sm, 4, 64);
      sm += __shfl_xor(sm, 8, 64);
      l_run[r] = l_run[r] * corr[r] + sm;
#pragma unroll
      for (int nt2 = 0; nt2 < 4; ++nt2) {
        acc1[nt2][r] *= corr[r];
        acc2[nt2][r] *= corr[r];
      }
    }

#pragma unroll
    for (int kk = 0; kk < 2; ++kk) {
      const unsigned int* prow = ldsP + arow * 68 + kk * 32 + agrp * 8;
      u32x4v w0 = *(const u32x4v*)prow;
      u32x4v w1 = *(const u32x4v*)(prow + 4);
      bf16x8 pa_h, pa_l;
#pragma unroll
      for (int i = 0; i < 4; ++i) {
        pa_h[i]     = (short)(w0[i] & 0xffffu);
        pa_l[i]     = (short)(w0[i] >> 16);
        pa_h[4 + i] = (short)(w1[i] & 0xffffu);
        pa_l[4 + i] = (short)(w1[i] >> 16);
      }
#pragma unroll
      for (int nt2 = 0; nt2 < 4; ++nt2) {
        const int vrow = nt2 * 16 + arow;
        const int chunk = kk * 4 + agrp;
        const int off = vrow * 128 + (((chunk ^ (vrow & 7)) << 4));
        bf16x8 vh_ = *(const bf16x8*)(ldsA_hi + off);
        bf16x8 vl_ = *(const bf16x8*)(ldsA_lo + off);
        acc1[nt2] = __builtin_amdgcn_mfma_f32_16x16x32_bf16(pa_h, vh_, acc1[nt2], 0, 0, 0);
        acc1[nt2] = __builtin_amdgcn_mfma_f32_16x16x32_bf16(pa_h, vl_, acc1[nt2], 0, 0, 0);
        acc1[nt2] = __builtin_amdgcn_mfma_f32_16x16x32_bf16(pa_l, vh_, acc1[nt2], 0, 0, 0);
        bf16x8 uh_ = *(const bf16x8*)(ldsB_hi + off);
        bf16x8 ul_ = *(const bf16x8*)(ldsB_lo + off);
        acc2[nt2] = __builtin_amdgcn_mfma_f32_16x16x32_bf16(pa_h, uh_, acc2[nt2], 0, 0, 0);
        acc2[nt2] = __builtin_amdgcn_mfma_f32_16x16x32_bf16(pa_h, ul_, acc2[nt2], 0, 0, 0);
        acc2[nt2] = __builtin_amdgcn_mfma_f32_16x16x32_bf16(pa_l, uh_, acc2[nt2], 0, 0, 0);
      }
    }
  }

#pragma unroll
  for (int r = 0; r < 4; ++r) {
    const float inv = 1.f / l_run[r];
    const int n = q0 + agrp * 4 + r;
    float* rowp = out1 + (size_t)b * (2048 * C_DIM) + (size_t)n * C_DIM + h * HD + arow;
    const size_t obase = ((size_t)(b * NSEQ + n)) * C_DIM + h * HD + arow;
#pragma unroll
    for (int nt2 = 0; nt2 < 4; ++nt2) {
      rowp[nt2 * 16] = acc1[nt2][r] * inv;
      unsigned short hi, lo;
      split2(acc2[nt2][r] * inv, hi, lo);
      osph[obase + nt2 * 16] = hi;
      ospl[obase + nt2 * 16] = lo;
    }
  }
}

// ---------------------------------------------------------------------------
extern "C" void kernel_launch(void* const* d_in, const int* in_sizes, int n_in,
                              void* d_out, int out_size, void* d_ws, size_t ws_size,
                              hipStream_t stream)
{
  const float* x           = (const float*)d_in[0];
  const float* w_qkv_diff  = (const float*)d_in[1];
  const float* w_qkv_cond  = (const float*)d_in[2];
  const float* w_proj_diff = (const float*)d_in[3];
  const float* b_proj_diff = (const float*)d_in[4];
  const float* w_proj_cond = (const float*)d_in[5];
  const float* b_proj_cond = (const float*)d_in[6];
  float* out = (float*)d_out;

  const size_t SZ = SZC;
  const size_t WQ = 2304 * 768;
  const size_t WP = 768 * 768;
  unsigned short* sw = (unsigned short*)d_ws;
  unsigned short* qd_hi  = sw + 0 * SZ;
  unsigned short* qd_lo  = sw + 1 * SZ;
  unsigned short* kd_hi  = sw + 2 * SZ;
  unsigned short* kd_lo  = sw + 3 * SZ;
  unsigned short* vtd_hi = sw + 4 * SZ;
  unsigned short* vtd_lo = sw + 5 * SZ;
  unsigned short* qc_hi  = sw + 6 * SZ;
  unsigned short* qc_lo  = sw + 7 * SZ;
  unsigned short* kc_hi  = sw + 8 * SZ;
  unsigned short* kc_lo  = sw + 9 * SZ;
  unsigned short* vtc_hi = sw + 10 * SZ;
  unsigned short* vtc_lo = sw + 11 * SZ;
  unsigned short* wqdT_h = sw + 12 * SZ;
  unsigned short* wqdT_l = wqdT_h + WQ;
  unsigned short* wqcT_h = wqdT_l + WQ;
  unsigned short* wqcT_l = wqcT_h + WQ;
  unsigned short* wpdT_h = wqcT_l + WQ;
  unsigned short* wpdT_l = wpdT_h + WP;
  unsigned short* wpcT_h = wpdT_l + WP;
  unsigned short* wpcT_l = wpcT_h + WP;
  unsigned short* osph = wqdT_h;          // aliases wq*T (dead after qkv)
  unsigned short* ospl = wqdT_h + SZ;
  unsigned short* vt2_hi = qd_hi;         // aliases q_d (dead after step 2)
  unsigned short* vt2_lo = qd_lo;

  // 0. weight prep
  split_wT_k<<<dim3(72, 24), dim3(32, 8), 0, stream>>>(w_qkv_diff, 768, 2304, wqdT_h, wqdT_l);
  split_wT_k<<<dim3(72, 24), dim3(32, 8), 0, stream>>>(w_qkv_cond, 768, 2304, wqcT_h, wqcT_l);
  split_wT_k<<<dim3(24, 24), dim3(32, 8), 0, stream>>>(w_proj_diff, 768, 768, wpdT_h, wpdT_l);
  split_wT_k<<<dim3(24, 24), dim3(32, 8), 0, stream>>>(w_proj_cond, 768, 768, wpcT_h, wpcT_l);

  // 1. qkv both streams
  qkv_gemm_k<<<dim3(18, 32, 2), 256, 0, stream>>>(
      x, wqdT_h, wqdT_l, wqcT_h, wqcT_l, sw);

  // 2. attn_diff -> osp split
  attn_single_k<<<dim3(16, 12, 4), 256, 0, stream>>>(
      qd_hi, qd_lo, kd_hi, kd_lo, vtd_hi, vtd_lo, osph, ospl);

  // 3. (osp @ w_proj_diff + b)^T split -> vt2
  proj_gemm_k<2><<<dim3(6, 32), 256, 0, stream>>>(
      osph, ospl, wpdT_h, wpdT_l, b_proj_diff, nullptr, vt2_hi, vt2_lo);

  // 4+5. fused attn_cond: P @ vt2 -> out[:, :N] fp32 ; P @ vt_c -> osp split
  attn_fused_k<<<dim3(16, 12, 4), 256, 0, stream>>>(
      qc_hi, qc_lo, kc_hi, kc_lo, vt2_hi, vt2_lo, vtc_hi, vtc_lo, out, osph, ospl);

  // 6. out[:, N:] = osp @ w_proj_cond + b
  proj_gemm_k<1><<<dim3(6, 32), 256, 0, stream>>>(
      osph, ospl, wpcT_h, wpcT_l, b_proj_cond, out, nullptr, nullptr);
}